// Round 2
// baseline (2846.158 us; speedup 1.0000x reference)
//
#include <hip/hip_runtime.h>
#include <hip/hip_bf16.h>
#include <type_traits>

typedef __bf16 bf16_t;
typedef __bf16 bf16x8 __attribute__((ext_vector_type(8)));
typedef float floatx4 __attribute__((ext_vector_type(4)));
typedef short v2s __attribute__((ext_vector_type(2)));

#define NN 50000
#define EE 800000
#define DD 128

// ---- ws layout (bytes) ----
#define W1T_OFF   256                                  // [128][288] (K 272->288 zero-pad)
#define W2T_OFF   (W1T_OFF + (size_t)128 * 288 * 2)    // [128][128]
#define NW1T_OFF  (W2T_OFF + (size_t)128 * 128 * 2)    // [128][256]
#define NW2T_OFF  (NW1T_OFF + (size_t)128 * 256 * 2)   // [128][128]
#define BIASF_OFF (NW2T_OFF + (size_t)128 * 128 * 2)   // float[512]: b1|b2|nb1|nb2
#define XB_OFF    207360                               // bf16 x copy [NN][DD]
#define AGG_OFF   (XB_OFF + (size_t)NN * DD * 2)       // bf16 agg [NN][DD]
#define AGG_BYTES ((size_t)NN * DD * 2)
#define WS_V2     (AGG_OFF + AGG_BYTES)                // 25,807,360 (proven available)
#define P_OFF     WS_V2                                // bf16 P = x @ eW1[0:128]
#define Q_OFF     (P_OFF + (size_t)NN * DD * 2)        // bf16 Q = x @ eW1[128:256]
#define WS_V3     (Q_OFF + (size_t)NN * DD * 2)        // 51,407,360 (proven available)
// v5: 8-bin counting sort of edges by destination row (XCD-local atomics)
#define PERM_OFF  WS_V3                                // int[EE]  original edge id, binned order
#define ROWS_OFF  (PERM_OFF + (size_t)EE * 4)          // int[EE]  clamped row, binned order
#define COLS_OFF  (ROWS_OFF + (size_t)EE * 4)          // int[EE]  clamped col, binned order
#define BINS_OFF  (COLS_OFF + (size_t)EE * 4)          // int[64]: cnt[8] | binStart[9] | offW[8]
#define WS_V5     (BINS_OFF + 256)                     // ~61.0 MB

#define NTILES (EE / 64)      // 12500 exact

// LDS pitches (bf16 elems)
#define PA 304   // v2 edge A pitch
#define PB 48    // B chunk pitch (32 + 16 pad)
#define PN 272   // node A pitch (256 + 16 pad)
#define PH 136   // h/x pitch (128 + 8 pad; 272B rows, 16B-aligned)

// ---- dtype-detect ----
__global__ void detect_kernel(const unsigned short* __restrict__ xraw,
                              const unsigned int* __restrict__ eiraw,
                              int* __restrict__ flags)
{
    int cnt = 0;
    for (int i = 0; i < 64; ++i) {
        unsigned short u = xraw[2 * i];
        int ex = (u >> 7) & 0xFF;
        if (ex >= 100 && ex <= 140) cnt++;
    }
    flags[0] = (cnt < 32) ? 1 : 0;   // 1 => fp32
    int zc = 0;
    for (int i = 0; i < 32; ++i)
        if (eiraw[2 * i + 1] == 0u) zc++;
    flags[1] = (zc >= 16) ? 1 : 0;   // 1 => int64
}

__device__ inline int load_idx(const void* ei, int i64, size_t pos)
{
    return i64 ? (int)((const long long*)ei)[pos] : ((const int*)ei)[pos];
}

// silu via v_rcp_f32: avoids the exact-div sequence; error << bf16 rounding.
__device__ inline float fast_silu(float v)
{
    float e = __expf(-v);
    return v * __builtin_amdgcn_rcpf(1.0f + e);
}

template <typename FT>
__device__ inline void cp8(bf16_t* dst, const FT* src)
{
    if constexpr (std::is_same<FT, float>::value) {
#pragma unroll
        for (int i = 0; i < 8; i += 4) {
            float4 v = *(const float4*)(src + i);
            dst[i + 0] = (bf16_t)v.x; dst[i + 1] = (bf16_t)v.y;
            dst[i + 2] = (bf16_t)v.z; dst[i + 3] = (bf16_t)v.w;
        }
    } else {
        *(bf16x8*)dst = *(const bf16x8*)src;
    }
}

__device__ inline void pk_atomic_add_bf16(bf16_t* addr, float lo, float hi)
{
#if __has_builtin(__builtin_amdgcn_global_atomic_fadd_v2bf16)
    union { bf16_t b[2]; v2s s; } pk;
    pk.b[0] = (bf16_t)lo;
    pk.b[1] = (bf16_t)hi;
    (void)__builtin_amdgcn_global_atomic_fadd_v2bf16((v2s*)addr, pk.s);
#else
    unsigned int* w = (unsigned int*)addr;
    unsigned int old = __hip_atomic_load(w, __ATOMIC_RELAXED, __HIP_MEMORY_SCOPE_AGENT);
    while (true) {
        union { unsigned int u; bf16_t b[2]; } cur;
        cur.u = old;
        cur.b[0] = (bf16_t)((float)cur.b[0] + lo);
        cur.b[1] = (bf16_t)((float)cur.b[1] + hi);
        unsigned int prev = atomicCAS(w, old, cur.u);
        if (prev == old) break;
        old = prev;
    }
#endif
}

// ---- binning: 8 bins by destination row (bin i -> XCD i) ----
__global__ __launch_bounds__(256) void bin_count_kernel(
    const void* __restrict__ ei, int* __restrict__ bins, const int* __restrict__ flags)
{
    const int i64 = flags[1];
    const int lane = threadIdx.x & 63;
    size_t e = (size_t)blockIdx.x * 256 + threadIdx.x;   // grid sized exactly: EE threads
    int row = min(max(load_idx(ei, i64, e), 0), NN - 1);
    int b = (row * 8) / NN;
#pragma unroll
    for (int bb = 0; bb < 8; ++bb) {
        unsigned long long mask = __ballot(b == bb);
        if (lane == 0 && mask) atomicAdd(&bins[bb], (int)__popcll(mask));
    }
}

__global__ void bin_prefix_kernel(int* __restrict__ bins)
{
    if (threadIdx.x == 0 && blockIdx.x == 0) {
        int* binStart = bins + 8;    // [9]
        int* offW     = bins + 17;   // [8]
        int s = 0;
        for (int i = 0; i < 8; ++i) {
            binStart[i] = s;
            offW[i] = s;
            s += bins[i];
        }
        binStart[8] = s;             // == EE
    }
}

__global__ __launch_bounds__(256) void bin_scatter_kernel(
    const void* __restrict__ ei, int* __restrict__ bins,
    int* __restrict__ perm, int* __restrict__ rowS, int* __restrict__ colS,
    const int* __restrict__ flags)
{
    const int i64 = flags[1];
    int* offW = bins + 17;
    const int lane = threadIdx.x & 63;
    size_t e = (size_t)blockIdx.x * 256 + threadIdx.x;
    int row = min(max(load_idx(ei, i64, e), 0), NN - 1);
    int col = min(max(load_idx(ei, i64, (size_t)EE + e), 0), NN - 1);
    int b = (row * 8) / NN;
    int pos = 0;
#pragma unroll
    for (int bb = 0; bb < 8; ++bb) {
        unsigned long long mask = __ballot(b == bb);
        if (b == bb) {
            int leader = __ffsll(mask) - 1;
            int rank = (int)__popcll(mask & ((1ull << lane) - 1ull));
            int base = 0;
            if (lane == leader) base = atomicAdd(&offW[bb], (int)__popcll(mask));
            base = __shfl(base, leader, 64);
            pos = base + rank;
        }
    }
    perm[pos] = (int)e;
    rowS[pos] = row;
    colS[pos] = col;
}

// ---- prep: transpose weights -> bf16 ws; biases -> float ws ----
template <typename FT>
__global__ __launch_bounds__(256) void prep_kernel(
    const FT* __restrict__ eW1, const FT* __restrict__ eW2,
    const FT* __restrict__ nW1, const FT* __restrict__ nW2,
    const FT* __restrict__ b1, const FT* __restrict__ b2,
    const FT* __restrict__ nb1, const FT* __restrict__ nb2,
    bf16_t* __restrict__ W1t, bf16_t* __restrict__ W2t,
    bf16_t* __restrict__ nW1t, bf16_t* __restrict__ nW2t,
    float* __restrict__ biasF, const int* __restrict__ flags)
{
    constexpr int WANT = std::is_same<FT, float>::value ? 1 : 0;
    if (flags[0] != WANT) return;
    int idx = blockIdx.x * 256 + threadIdx.x;
    if (idx < 128 * 288) {
        int n = idx / 288;
        int k = idx - n * 288;
        W1t[idx] = (k < 272) ? (bf16_t)(float)eW1[k * 128 + n] : (bf16_t)0.0f;
    } else if (idx < 128 * 288 + 128 * 128) {
        int j = idx - 128 * 288;
        int n = j >> 7, k = j & 127;
        W2t[j] = (bf16_t)(float)eW2[k * 128 + n];
    } else if (idx < 128 * 288 + 128 * 128 + 128 * 256) {
        int j = idx - (128 * 288 + 128 * 128);
        int n = j >> 8, k = j & 255;
        nW1t[j] = (bf16_t)(float)nW1[k * 128 + n];
    } else if (idx < 102400) {
        int j = idx - (128 * 288 + 128 * 128 + 128 * 256);
        int n = j >> 7, k = j & 127;
        nW2t[j] = (bf16_t)(float)nW2[k * 128 + n];
    } else if (idx < 102912) {
        int j = idx - 102400;
        int which = j >> 7, c = j & 127;
        const FT* src = which == 0 ? b1 : which == 1 ? b2 : which == 2 ? nb1 : nb2;
        biasF[j] = (float)src[c];
    }
}

// ---- conv_x: x (FT) -> xb (bf16) ----
template <typename FT>
__global__ __launch_bounds__(256) void conv_x_kernel(
    const FT* __restrict__ x, bf16_t* __restrict__ xb,
    const int* __restrict__ flags)
{
    constexpr int WANT = std::is_same<FT, float>::value ? 1 : 0;
    if (flags[0] != WANT) return;
    size_t i = ((size_t)blockIdx.x * 256 + threadIdx.x) * 8;
    if (i >= (size_t)NN * DD) return;
    bf16x8 v;
    if constexpr (std::is_same<FT, float>::value) {
        float4 a = *(const float4*)(x + i);
        float4 b = *(const float4*)(x + i + 4);
        v[0] = (bf16_t)a.x; v[1] = (bf16_t)a.y; v[2] = (bf16_t)a.z; v[3] = (bf16_t)a.w;
        v[4] = (bf16_t)b.x; v[5] = (bf16_t)b.y; v[6] = (bf16_t)b.z; v[7] = (bf16_t)b.w;
    } else {
        v = *(const bf16x8*)(x + i);
    }
    *(bf16x8*)(xb + i) = v;
}

// ---- pq: P = xb @ eW1[0:128], Q = xb @ eW1[128:256] (both bf16 to ws) ----
__global__ __launch_bounds__(256) void pq_kernel(
    const bf16_t* __restrict__ xb, const bf16_t* __restrict__ W1t,
    bf16_t* __restrict__ P, bf16_t* __restrict__ Q)
{
    __shared__ bf16_t sX[64 * PH];
    __shared__ bf16_t sB[128 * PB];
    const int tid = threadIdx.x;
    const int n0 = blockIdx.x * 64;

    {
        const int m = tid >> 2;
        const int part = tid & 3;
        int n = n0 + m;
        if (n >= NN) n = NN - 1;
        const bf16x8* src = (const bf16x8*)(xb + (size_t)n * DD + part * 32);
        bf16x8* dst = (bf16x8*)&sX[m * PH + part * 32];
#pragma unroll
        for (int i = 0; i < 4; ++i) dst[i] = src[i];
    }

    const int lane = tid & 63;
    const int wv = tid >> 6;
    const int ml = lane & 15;
    const int q = lane >> 4;
    const int m0 = wv * 16;
    const floatx4 fzero = {0.f, 0.f, 0.f, 0.f};

    for (int pass = 0; pass < 2; ++pass) {
        floatx4 acc[8];
#pragma unroll
        for (int i = 0; i < 8; ++i) acc[i] = fzero;

        for (int kc = 0; kc < 4; ++kc) {
            __syncthreads();
            {
                const int n = tid >> 1;
                const int half = tid & 1;
                const bf16x8* src = (const bf16x8*)(W1t + n * 288 + pass * 128 + kc * 32 + half * 16);
                bf16x8* dst = (bf16x8*)&sB[n * PB + half * 16];
                dst[0] = src[0];
                dst[1] = src[1];
            }
            __syncthreads();
            const bf16x8 a = *(const bf16x8*)&sX[(m0 + ml) * PH + kc * 32 + q * 8];
#pragma unroll
            for (int nt = 0; nt < 8; ++nt) {
                const bf16x8 b = *(const bf16x8*)&sB[(nt * 16 + ml) * PB + q * 8];
                acc[nt] = __builtin_amdgcn_mfma_f32_16x16x32_bf16(a, b, acc[nt], 0, 0, 0);
            }
        }

        bf16_t* dst = pass ? Q : P;
#pragma unroll
        for (int r = 0; r < 4; ++r) {
            const int n = n0 + m0 + q * 4 + r;
#pragma unroll
            for (int nt = 0; nt < 8; ++nt) {
                float v = acc[nt][r];
                const float pv = __shfl_xor(v, 1, 64);
                if (((lane & 1) == 0) && n < NN) {
                    union { bf16_t b[2]; unsigned int u; } pk;
                    pk.b[0] = (bf16_t)v;
                    pk.b[1] = (bf16_t)pv;
                    *(unsigned int*)(dst + (size_t)n * DD + nt * 16 + ml) = pk.u;
                }
            }
        }
    }
}

// ======== edge v5: v3 structure + binned edge order + XCD-pinned bins ========
// Block b processes tiles of bin (b%8) only => with round-robin block->XCD
// dispatch, all agg atomics (and P-row gathers) of XCD i hit a 1.6 MB slice
// resident in its private L2. Correctness independent of the mapping.
__global__ __launch_bounds__(256) void edge_kernel_v5(
    const int* __restrict__ perm, const int* __restrict__ rowS,
    const int* __restrict__ colS, const void* __restrict__ ea,
    const bf16_t* __restrict__ P, const bf16_t* __restrict__ Q,
    const bf16_t* __restrict__ W1t, const bf16_t* __restrict__ W2t,
    const float* __restrict__ biasF, const int* __restrict__ bins,
    bf16_t* __restrict__ agg, const int* __restrict__ flags)
{
    const int f32 = flags[0];
    const int* binStart = bins + 8;

    __shared__ bf16_t sH[64 * PH];    // P+Q sum, then h (layer-2 A operand)
    __shared__ bf16_t sEA[64 * 32];   // ea tile, k 16..31 zero
    __shared__ bf16_t sB[128 * PB];   // B staging: ea-chunk of W1t, then W2 chunks
    __shared__ int    sIdx[64];       // clamped dest row per edge

    const int tid = threadIdx.x;
    const int bin  = blockIdx.x & 7;
    const int rank = blockIdx.x >> 3;
    const int nb   = gridDim.x >> 3;
    const int tLo  = (binStart[bin] + 63) >> 6;
    const int tHi  = (bin == 7) ? NTILES : ((binStart[bin + 1] + 63) >> 6);

    const int lane = tid & 63;
    const int wv = tid >> 6;
    const int ml = lane & 15;
    const int q = lane >> 4;
    const int m0 = wv * 16;
    const floatx4 fzero = {0.f, 0.f, 0.f, 0.f};

    for (int t = tLo + rank; t < tHi; t += nb) {
        // ---- stage: sH = bf16(P[row]+Q[col]); sEA; sB = W1t ea-chunk ----
        {
            const int m = tid >> 2;
            const int part = tid & 3;
            const int epos = t * 64 + m;
            const int rn = rowS[epos];
            const int cn = colS[epos];
            if (part == 0) sIdx[m] = rn;
            const bf16x8* pr = (const bf16x8*)(P + (size_t)rn * DD + part * 32);
            const bf16x8* qc = (const bf16x8*)(Q + (size_t)cn * DD + part * 32);
#pragma unroll
            for (int i = 0; i < 4; ++i) {
                bf16x8 a = pr[i], b = qc[i], o;
#pragma unroll
                for (int j = 0; j < 8; ++j) o[j] = (bf16_t)((float)a[j] + (float)b[j]);
                *(bf16x8*)&sH[m * PH + part * 32 + i * 8] = o;
            }
            if (part < 2) {
                const int ep = perm[epos];
                if (f32) cp8<float>(&sEA[m * 32 + part * 8], (const float*)ea + (size_t)ep * 16 + part * 8);
                else     cp8<bf16_t>(&sEA[m * 32 + part * 8], (const bf16_t*)ea + (size_t)ep * 16 + part * 8);
            } else {
                *(float4*)&sEA[m * 32 + part * 8] = make_float4(0.f, 0.f, 0.f, 0.f);
            }
            {
                const int n = tid >> 1;
                const int half = tid & 1;
                const bf16x8* src = (const bf16x8*)(W1t + n * 288 + 256 + half * 16);
                bf16x8* dst = (bf16x8*)&sB[n * PB + half * 16];
                dst[0] = src[0];
                dst[1] = src[1];
            }
        }
        __syncthreads();

        // ---- ea contribution: one K=32 MFMA chunk ----
        floatx4 acc[8];
        {
            const bf16x8 a = *(const bf16x8*)&sEA[(m0 + ml) * 32 + q * 8];
#pragma unroll
            for (int nt = 0; nt < 8; ++nt) {
                const bf16x8 b = *(const bf16x8*)&sB[(nt * 16 + ml) * PB + q * 8];
                acc[nt] = __builtin_amdgcn_mfma_f32_16x16x32_bf16(a, b, fzero, 0, 0, 0);
            }
        }

        // ---- h = silu(acc + (P+Q) + b1), in place (wave-local rows) ----
#pragma unroll
        for (int nt = 0; nt < 8; ++nt) {
            const float bias = biasF[nt * 16 + ml];
#pragma unroll
            for (int r = 0; r < 4; ++r) {
                const int row = m0 + q * 4 + r;
                const int col = nt * 16 + ml;
                float v = acc[nt][r] + bias + (float)sH[row * PH + col];
                sH[row * PH + col] = (bf16_t)fast_silu(v);
            }
        }

        floatx4 acc2[8];
#pragma unroll
        for (int i = 0; i < 8; ++i) acc2[i] = fzero;

        // ---- layer 2: [64x128] @ [128x128], 4 K-chunks ----
        for (int kc = 0; kc < 4; ++kc) {
            __syncthreads();
            {
                const int n = tid >> 1;
                const int half = tid & 1;
                const bf16x8* src = (const bf16x8*)(W2t + n * 128 + kc * 32 + half * 16);
                bf16x8* dst = (bf16x8*)&sB[n * PB + half * 16];
                dst[0] = src[0];
                dst[1] = src[1];
            }
            __syncthreads();
            const bf16x8 a = *(const bf16x8*)&sH[(m0 + ml) * PH + kc * 32 + q * 8];
#pragma unroll
            for (int nt = 0; nt < 8; ++nt) {
                const bf16x8 b = *(const bf16x8*)&sB[(nt * 16 + ml) * PB + q * 8];
                acc2[nt] = __builtin_amdgcn_mfma_f32_16x16x32_bf16(a, b, acc2[nt], 0, 0, 0);
            }
        }

        // ---- m_ij = silu(acc2 + b2); pk-bf16 scatter (L2-local rows) ----
#pragma unroll
        for (int r = 0; r < 4; ++r) {
            const int rs = sIdx[m0 + q * 4 + r];
            bf16_t* base = agg + (size_t)rs * DD;
#pragma unroll
            for (int nt = 0; nt < 8; ++nt) {
                float v = fast_silu(acc2[nt][r] + biasF[128 + nt * 16 + ml]);
                const float pv = __shfl_xor(v, 1, 64);
                if ((ml & 1) == 0)
                    pk_atomic_add_bf16(base + nt * 16 + ml, v, pv);
            }
        }
        __syncthreads();   // sB/sH reused next iteration (cross-wave readers)
    }
}

// ======== edge v3 (fallback: ws fits P/Q but not binning arrays) ========
__global__ __launch_bounds__(256) void edge_kernel_v3(
    const void* __restrict__ ei, const void* __restrict__ ea,
    const bf16_t* __restrict__ P, const bf16_t* __restrict__ Q,
    const bf16_t* __restrict__ W1t, const bf16_t* __restrict__ W2t,
    const float* __restrict__ biasF,
    bf16_t* __restrict__ agg, const int* __restrict__ flags)
{
    const int f32 = flags[0];
    const int i64 = flags[1];

    __shared__ bf16_t sH[64 * PH];
    __shared__ bf16_t sEA[64 * 32];
    __shared__ bf16_t sB[128 * PB];
    const int tid = threadIdx.x;
    const int e0 = blockIdx.x * 64;

    {
        const int m = tid >> 2;
        const int part = tid & 3;
        const int e = e0 + m;
        int rn = load_idx(ei, i64, e);
        int cn = load_idx(ei, i64, (size_t)EE + e);
        rn = min(max(rn, 0), NN - 1);
        cn = min(max(cn, 0), NN - 1);
        const bf16x8* pr = (const bf16x8*)(P + (size_t)rn * DD + part * 32);
        const bf16x8* qc = (const bf16x8*)(Q + (size_t)cn * DD + part * 32);
#pragma unroll
        for (int i = 0; i < 4; ++i) {
            bf16x8 a = pr[i], b = qc[i], o;
#pragma unroll
            for (int j = 0; j < 8; ++j) o[j] = (bf16_t)((float)a[j] + (float)b[j]);
            *(bf16x8*)&sH[m * PH + part * 32 + i * 8] = o;
        }
        if (part < 2) {
            if (f32) cp8<float>(&sEA[m * 32 + part * 8], (const float*)ea + (size_t)e * 16 + part * 8);
            else     cp8<bf16_t>(&sEA[m * 32 + part * 8], (const bf16_t*)ea + (size_t)e * 16 + part * 8);
        } else {
            *(float4*)&sEA[m * 32 + part * 8] = make_float4(0.f, 0.f, 0.f, 0.f);
        }
        {
            const int n = tid >> 1;
            const int half = tid & 1;
            const bf16x8* src = (const bf16x8*)(W1t + n * 288 + 256 + half * 16);
            bf16x8* dst = (bf16x8*)&sB[n * PB + half * 16];
            dst[0] = src[0];
            dst[1] = src[1];
        }
    }
    __syncthreads();

    const int lane = tid & 63;
    const int wv = tid >> 6;
    const int ml = lane & 15;
    const int q = lane >> 4;
    const int m0 = wv * 16;
    const floatx4 fzero = {0.f, 0.f, 0.f, 0.f};

    floatx4 acc[8];
#pragma unroll
    for (int i = 0; i < 8; ++i) acc[i] = fzero;
    {
        const bf16x8 a = *(const bf16x8*)&sEA[(m0 + ml) * 32 + q * 8];
#pragma unroll
        for (int nt = 0; nt < 8; ++nt) {
            const bf16x8 b = *(const bf16x8*)&sB[(nt * 16 + ml) * PB + q * 8];
            acc[nt] = __builtin_amdgcn_mfma_f32_16x16x32_bf16(a, b, acc[nt], 0, 0, 0);
        }
    }

#pragma unroll
    for (int nt = 0; nt < 8; ++nt) {
        const float bias = biasF[nt * 16 + ml];
#pragma unroll
        for (int r = 0; r < 4; ++r) {
            const int row = m0 + q * 4 + r;
            const int col = nt * 16 + ml;
            float v = acc[nt][r] + bias + (float)sH[row * PH + col];
            sH[row * PH + col] = (bf16_t)fast_silu(v);
        }
    }

    floatx4 acc2[8];
#pragma unroll
    for (int i = 0; i < 8; ++i) acc2[i] = fzero;

    for (int kc = 0; kc < 4; ++kc) {
        __syncthreads();
        {
            const int n = tid >> 1;
            const int half = tid & 1;
            const bf16x8* src = (const bf16x8*)(W2t + n * 128 + kc * 32 + half * 16);
            bf16x8* dst = (bf16x8*)&sB[n * PB + half * 16];
            dst[0] = src[0];
            dst[1] = src[1];
        }
        __syncthreads();
        const bf16x8 a = *(const bf16x8*)&sH[(m0 + ml) * PH + kc * 32 + q * 8];
#pragma unroll
        for (int nt = 0; nt < 8; ++nt) {
            const bf16x8 b = *(const bf16x8*)&sB[(nt * 16 + ml) * PB + q * 8];
            acc2[nt] = __builtin_amdgcn_mfma_f32_16x16x32_bf16(a, b, acc2[nt], 0, 0, 0);
        }
    }

#pragma unroll
    for (int r = 0; r < 4; ++r) {
        const int e = e0 + m0 + q * 4 + r;
        int rn = load_idx(ei, i64, e);
        rn = min(max(rn, 0), NN - 1);
#pragma unroll
        for (int nt = 0; nt < 8; ++nt) {
            float v = fast_silu(acc2[nt][r] + biasF[128 + nt * 16 + ml]);
            const float pv = __shfl_xor(v, 1, 64);
            if ((ml & 1) == 0)
                pk_atomic_add_bf16(agg + (size_t)rn * DD + nt * 16 + ml, v, pv);
        }
    }
}

// ======== edge v2 (fallback if ws too small for P/Q) ========
__global__ __launch_bounds__(256) void edge_kernel_v2(
    const bf16_t* __restrict__ xb, const void* __restrict__ ei,
    const void* __restrict__ ea,
    const bf16_t* __restrict__ W1t, const bf16_t* __restrict__ W2t,
    const float* __restrict__ biasF,
    bf16_t* __restrict__ agg, const int* __restrict__ flags)
{
    const int f32 = flags[0];
    const int i64 = flags[1];

    __shared__ bf16_t sA[64 * PA];
    __shared__ bf16_t sB[128 * PB];
    const int tid = threadIdx.x;
    const int e0 = blockIdx.x * 64;

    {
        const int m = tid >> 2;
        const int part = tid & 3;
        const int e = e0 + m;
        int rn = load_idx(ei, i64, e);
        int cn = load_idx(ei, i64, (size_t)EE + e);
        rn = min(max(rn, 0), NN - 1);
        cn = min(max(cn, 0), NN - 1);
        const bf16x8* xr = (const bf16x8*)(xb + (size_t)rn * DD + part * 32);
        const bf16x8* xc = (const bf16x8*)(xb + (size_t)cn * DD + part * 32);
        bf16x8* dR = (bf16x8*)&sA[m * PA + part * 32];
        bf16x8* dC = (bf16x8*)&sA[m * PA + 128 + part * 32];
#pragma unroll
        for (int i = 0; i < 4; ++i) dR[i] = xr[i];
#pragma unroll
        for (int i = 0; i < 4; ++i) dC[i] = xc[i];
        if (part < 2) {
            if (f32) cp8<float>(&sA[m * PA + 256 + part * 8], (const float*)ea + (size_t)e * 16 + part * 8);
            else     cp8<bf16_t>(&sA[m * PA + 256 + part * 8], (const bf16_t*)ea + (size_t)e * 16 + part * 8);
        } else {
            *(float4*)&sA[m * PA + 256 + part * 8] = make_float4(0.f, 0.f, 0.f, 0.f);
        }
    }

    const int lane = tid & 63;
    const int wv = tid >> 6;
    const int ml = lane & 15;
    const int q = lane >> 4;
    const int m0 = wv * 16;

    const floatx4 fzero = {0.f, 0.f, 0.f, 0.f};
    floatx4 acc[8];
#pragma unroll
    for (int i = 0; i < 8; ++i) acc[i] = fzero;

    for (int kc = 0; kc < 9; ++kc) {
        __syncthreads();
        {
            const int n = tid >> 1;
            const int half = tid & 1;
            const bf16x8* src = (const bf16x8*)(W1t + n * 288 + kc * 32 + half * 16);
            bf16x8* dst = (bf16x8*)&sB[n * PB + half * 16];
            dst[0] = src[0];
            dst[1] = src[1];
        }
        __syncthreads();
        const bf16x8 a = *(const bf16x8*)&sA[(m0 + ml) * PA + kc * 32 + q * 8];
#pragma unroll
        for (int nt = 0; nt < 8; ++nt) {
            const bf16x8 b = *(const bf16x8*)&sB[(nt * 16 + ml) * PB + q * 8];
            acc[nt] = __builtin_amdgcn_mfma_f32_16x16x32_bf16(a, b, acc[nt], 0, 0, 0);
        }
    }

#pragma unroll
    for (int nt = 0; nt < 8; ++nt) {
        const float bias = biasF[nt * 16 + ml];
#pragma unroll
        for (int r = 0; r < 4; ++r) {
            float v = acc[nt][r] + bias;
            sA[(m0 + q * 4 + r) * PA + nt * 16 + ml] = (bf16_t)fast_silu(v);
        }
    }
    __syncthreads();

    floatx4 acc2[8];
#pragma unroll
    for (int i = 0; i < 8; ++i) acc2[i] = fzero;

    for (int kc = 0; kc < 4; ++kc) {
        __syncthreads();
        {
            const int n = tid >> 1;
            const int half = tid & 1;
            const bf16x8* src = (const bf16x8*)(W2t + n * 128 + kc * 32 + half * 16);
            bf16x8* dst = (bf16x8*)&sB[n * PB + half * 16];
            dst[0] = src[0];
            dst[1] = src[1];
        }
        __syncthreads();
        const bf16x8 a = *(const bf16x8*)&sA[(m0 + ml) * PA + kc * 32 + q * 8];
#pragma unroll
        for (int nt = 0; nt < 8; ++nt) {
            const bf16x8 b = *(const bf16x8*)&sB[(nt * 16 + ml) * PB + q * 8];
            acc2[nt] = __builtin_amdgcn_mfma_f32_16x16x32_bf16(a, b, acc2[nt], 0, 0, 0);
        }
    }

#pragma unroll
    for (int r = 0; r < 4; ++r) {
        const int e = e0 + m0 + q * 4 + r;
        int rn = load_idx(ei, i64, e);
        rn = min(max(rn, 0), NN - 1);
#pragma unroll
        for (int nt = 0; nt < 8; ++nt) {
            float v = fast_silu(acc2[nt][r] + biasF[128 + nt * 16 + ml]);
            const float pv = __shfl_xor(v, 1, 64);
            if ((ml & 1) == 0)
                pk_atomic_add_bf16(agg + (size_t)rn * DD + nt * 16 + ml, v, pv);
        }
    }
}

// -------- node MLP: out = x + (silu([xb|agg] @ nW1 + nb1) @ nW2 + nb2) --------
template <typename FT>
__global__ __launch_bounds__(256) void node_kernel_v2(
    const FT* __restrict__ x, const bf16_t* __restrict__ xb,
    const bf16_t* __restrict__ agg,
    const bf16_t* __restrict__ nW1t, const bf16_t* __restrict__ nW2t,
    const float* __restrict__ biasF,
    FT* __restrict__ out, const int* __restrict__ flags)
{
    constexpr int WANT = std::is_same<FT, float>::value ? 1 : 0;
    if (flags[0] != WANT) return;

    __shared__ bf16_t sA[64 * PN];
    __shared__ bf16_t sB[128 * PB];
    const int tid = threadIdx.x;
    const int n0 = blockIdx.x * 64;

    {
        const int m = tid >> 2;
        const int p = tid & 3;
        int n = n0 + m;
        if (n >= NN) n = NN - 1;
        const bf16_t* srcbase = (p < 2) ? xb : agg;
        const int col = (p & 1) * 64;
        const bf16x8* src = (const bf16x8*)(srcbase + (size_t)n * DD + col);
        bf16x8* dst = (bf16x8*)&sA[m * PN + (p >> 1) * 128 + col];
#pragma unroll
        for (int i = 0; i < 8; ++i) dst[i] = src[i];
    }

    const int lane = tid & 63;
    const int wv = tid >> 6;
    const int ml = lane & 15;
    const int q = lane >> 4;
    const int m0 = wv * 16;

    const floatx4 fzero = {0.f, 0.f, 0.f, 0.f};
    floatx4 acc[8];
#pragma unroll
    for (int i = 0; i < 8; ++i) acc[i] = fzero;

    for (int kc = 0; kc < 8; ++kc) {
        __syncthreads();
        {
            const int n = tid >> 1;
            const int half = tid & 1;
            const bf16x8* src = (const bf16x8*)(nW1t + n * 256 + kc * 32 + half * 16);
            bf16x8* dst = (bf16x8*)&sB[n * PB + half * 16];
            dst[0] = src[0];
            dst[1] = src[1];
        }
        __syncthreads();
        const bf16x8 a = *(const bf16x8*)&sA[(m0 + ml) * PN + kc * 32 + q * 8];
#pragma unroll
        for (int nt = 0; nt < 8; ++nt) {
            const bf16x8 b = *(const bf16x8*)&sB[(nt * 16 + ml) * PB + q * 8];
            acc[nt] = __builtin_amdgcn_mfma_f32_16x16x32_bf16(a, b, acc[nt], 0, 0, 0);
        }
    }

#pragma unroll
    for (int nt = 0; nt < 8; ++nt) {
        const float bias = biasF[256 + nt * 16 + ml];
#pragma unroll
        for (int r = 0; r < 4; ++r) {
            float v = acc[nt][r] + bias;
            sA[(m0 + q * 4 + r) * PN + nt * 16 + ml] = (bf16_t)fast_silu(v);
        }
    }
    __syncthreads();

    floatx4 acc2[8];
#pragma unroll
    for (int i = 0; i < 8; ++i) acc2[i] = fzero;

    for (int kc = 0; kc < 4; ++kc) {
        __syncthreads();
        {
            const int n = tid >> 1;
            const int half = tid & 1;
            const bf16x8* src = (const bf16x8*)(nW2t + n * 128 + kc * 32 + half * 16);
            bf16x8* dst = (bf16x8*)&sB[n * PB + half * 16];
            dst[0] = src[0];
            dst[1] = src[1];
        }
        __syncthreads();
        const bf16x8 a = *(const bf16x8*)&sA[(m0 + ml) * PN + kc * 32 + q * 8];
#pragma unroll
        for (int nt = 0; nt < 8; ++nt) {
            const bf16x8 b = *(const bf16x8*)&sB[(nt * 16 + ml) * PB + q * 8];
            acc2[nt] = __builtin_amdgcn_mfma_f32_16x16x32_bf16(a, b, acc2[nt], 0, 0, 0);
        }
    }

#pragma unroll
    for (int r = 0; r < 4; ++r) {
        const int n = n0 + m0 + q * 4 + r;
        if (n < NN) {
#pragma unroll
            for (int nt = 0; nt < 8; ++nt) {
                const int col = nt * 16 + ml;
                float v = acc2[nt][r] + biasF[384 + col];
                float xv = (float)x[(size_t)n * DD + col];
                out[(size_t)n * DD + col] = (FT)(xv + v);
            }
        }
    }
}

extern "C" void kernel_launch(void* const* d_in, const int* in_sizes, int n_in,
                              void* d_out, int out_size, void* d_ws, size_t ws_size,
                              hipStream_t stream)
{
    const void* x   = d_in[0];
    const void* ei  = d_in[1];
    const void* ea  = d_in[2];
    const void* eW1 = d_in[3];
    const void* eb1 = d_in[4];
    const void* eW2 = d_in[5];
    const void* eb2 = d_in[6];
    const void* nW1 = d_in[7];
    const void* nb1 = d_in[8];
    const void* nW2 = d_in[9];
    const void* nb2 = d_in[10];

    char* ws = (char*)d_ws;
    int*    flags = (int*)ws;
    bf16_t* W1t   = (bf16_t*)(ws + W1T_OFF);
    bf16_t* W2t   = (bf16_t*)(ws + W2T_OFF);
    bf16_t* nW1t  = (bf16_t*)(ws + NW1T_OFF);
    bf16_t* nW2t  = (bf16_t*)(ws + NW2T_OFF);
    float*  biasF = (float*)(ws + BIASF_OFF);
    bf16_t* xb    = (bf16_t*)(ws + XB_OFF);
    bf16_t* agg   = (bf16_t*)(ws + AGG_OFF);
    bf16_t* P     = (bf16_t*)(ws + P_OFF);
    bf16_t* Q     = (bf16_t*)(ws + Q_OFF);
    int*    perm  = (int*)(ws + PERM_OFF);
    int*    rowS  = (int*)(ws + ROWS_OFF);
    int*    colS  = (int*)(ws + COLS_OFF);
    int*    bins  = (int*)(ws + BINS_OFF);

    detect_kernel<<<1, 1, 0, stream>>>((const unsigned short*)x,
                                       (const unsigned int*)ei, flags);

    prep_kernel<bf16_t><<<403, 256, 0, stream>>>(
        (const bf16_t*)eW1, (const bf16_t*)eW2, (const bf16_t*)nW1, (const bf16_t*)nW2,
        (const bf16_t*)eb1, (const bf16_t*)eb2, (const bf16_t*)nb1, (const bf16_t*)nb2,
        W1t, W2t, nW1t, nW2t, biasF, flags);
    prep_kernel<float><<<403, 256, 0, stream>>>(
        (const float*)eW1, (const float*)eW2, (const float*)nW1, (const float*)nW2,
        (const float*)eb1, (const float*)eb2, (const float*)nb1, (const float*)nb2,
        W1t, W2t, nW1t, nW2t, biasF, flags);

    (void)hipMemsetAsync(agg, 0, AGG_BYTES, stream);
    conv_x_kernel<bf16_t><<<3125, 256, 0, stream>>>((const bf16_t*)x, xb, flags);
    conv_x_kernel<float><<<3125, 256, 0, stream>>>((const float*)x, xb, flags);

    if (ws_size >= WS_V5) {
        (void)hipMemsetAsync(bins, 0, 32, stream);
        bin_count_kernel<<<EE / 256, 256, 0, stream>>>(ei, bins, flags);
        bin_prefix_kernel<<<1, 1, 0, stream>>>(bins);
        bin_scatter_kernel<<<EE / 256, 256, 0, stream>>>(ei, bins, perm, rowS, colS, flags);
        pq_kernel<<<(NN + 63) / 64, 256, 0, stream>>>(xb, W1t, P, Q);
        edge_kernel_v5<<<12504, 256, 0, stream>>>(perm, rowS, colS, ea, P, Q,
                                                  W1t, W2t, biasF, bins, agg, flags);
    } else if (ws_size >= WS_V3) {
        pq_kernel<<<(NN + 63) / 64, 256, 0, stream>>>(xb, W1t, P, Q);
        edge_kernel_v3<<<EE / 64, 256, 0, stream>>>(ei, ea, P, Q, W1t, W2t, biasF, agg, flags);
    } else {
        edge_kernel_v2<<<EE / 64, 256, 0, stream>>>(xb, ei, ea, W1t, W2t, biasF, agg, flags);
    }

    node_kernel_v2<bf16_t><<<(NN + 63) / 64, 256, 0, stream>>>(
        (const bf16_t*)x, xb, agg, nW1t, nW2t, biasF, (bf16_t*)d_out, flags);
    node_kernel_v2<float><<<(NN + 63) / 64, 256, 0, stream>>>(
        (const float*)x, xb, agg, nW1t, nW2t, biasF, (float*)d_out, flags);
}

// Round 3
// 621.272 us; speedup vs baseline: 4.5812x; 4.5812x over previous
//
#include <hip/hip_runtime.h>
#include <hip/hip_bf16.h>
#include <type_traits>

typedef __bf16 bf16_t;
typedef __bf16 bf16x8 __attribute__((ext_vector_type(8)));
typedef float floatx4 __attribute__((ext_vector_type(4)));
typedef short v2s __attribute__((ext_vector_type(2)));

#define NN 50000
#define EE 800000
#define DD 128

// ---- ws layout (bytes) ----
#define W1T_OFF   256                                  // [128][288] (K 272->288 zero-pad)
#define W2T_OFF   (W1T_OFF + (size_t)128 * 288 * 2)    // [128][128]
#define NW1T_OFF  (W2T_OFF + (size_t)128 * 128 * 2)    // [128][256]
#define NW2T_OFF  (NW1T_OFF + (size_t)128 * 256 * 2)   // [128][128]
#define BIASF_OFF (NW2T_OFF + (size_t)128 * 128 * 2)   // float[512]: b1|b2|nb1|nb2
#define XB_OFF    207360                               // bf16 x copy [NN][DD]
#define AGG_OFF   (XB_OFF + (size_t)NN * DD * 2)       // bf16 agg [NN][DD]
#define AGG_BYTES ((size_t)NN * DD * 2)
#define WS_V2     (AGG_OFF + AGG_BYTES)                // 25,807,360 (proven available)
#define P_OFF     WS_V2                                // bf16 P = x @ eW1[0:128]
#define Q_OFF     (P_OFF + (size_t)NN * DD * 2)        // bf16 Q = x @ eW1[128:256]
#define WS_V3     (Q_OFF + (size_t)NN * DD * 2)        // 51,407,360 (proven available)
// v5: 8-bin counting sort of edges by destination row (XCD-local atomics).
// Deterministic 3-pass (hist -> scan -> scatter), ZERO global atomics.
#define PERM_OFF  WS_V3                                // int[EE]  original edge id, binned order
#define ROWS_OFF  (PERM_OFF + (size_t)EE * 4)          // int[EE]  clamped row, binned order
#define COLS_OFF  (ROWS_OFF + (size_t)EE * 4)          // int[EE]  clamped col, binned order
#define BCNT_OFF  (COLS_OFF + (size_t)EE * 4)          // int[8*NBLK_SORT] bin-major counts
#define BOFF_OFF  (BCNT_OFF + (size_t)8 * NBLK_SORT * 4) // int[8*NBLK_SORT] exclusive offsets
#define WS_V5     (BOFF_OFF + (size_t)8 * NBLK_SORT * 4) // ~61.2 MB

#define NTILES    (EE / 64)    // 12500 exact
#define NBLK_SORT (EE / 256)   // 3125 exact
#define SCAN_TOTAL (8 * NBLK_SORT)

// LDS pitches (bf16 elems)
#define PA 304   // v2 edge A pitch
#define PB 48    // B chunk pitch (32 + 16 pad)
#define PN 272   // node A pitch (256 + 16 pad)
#define PH 136   // h/x pitch (128 + 8 pad; 272B rows, 16B-aligned)

// ---- dtype-detect ----
__global__ void detect_kernel(const unsigned short* __restrict__ xraw,
                              const unsigned int* __restrict__ eiraw,
                              int* __restrict__ flags)
{
    int cnt = 0;
    for (int i = 0; i < 64; ++i) {
        unsigned short u = xraw[2 * i];
        int ex = (u >> 7) & 0xFF;
        if (ex >= 100 && ex <= 140) cnt++;
    }
    flags[0] = (cnt < 32) ? 1 : 0;   // 1 => fp32
    int zc = 0;
    for (int i = 0; i < 32; ++i)
        if (eiraw[2 * i + 1] == 0u) zc++;
    flags[1] = (zc >= 16) ? 1 : 0;   // 1 => int64
}

__device__ inline int load_idx(const void* ei, int i64, size_t pos)
{
    return i64 ? (int)((const long long*)ei)[pos] : ((const int*)ei)[pos];
}

// silu via v_rcp_f32: avoids the exact-div sequence; error << bf16 rounding.
__device__ inline float fast_silu(float v)
{
    float e = __expf(-v);
    return v * __builtin_amdgcn_rcpf(1.0f + e);
}

template <typename FT>
__device__ inline void cp8(bf16_t* dst, const FT* src)
{
    if constexpr (std::is_same<FT, float>::value) {
#pragma unroll
        for (int i = 0; i < 8; i += 4) {
            float4 v = *(const float4*)(src + i);
            dst[i + 0] = (bf16_t)v.x; dst[i + 1] = (bf16_t)v.y;
            dst[i + 2] = (bf16_t)v.z; dst[i + 3] = (bf16_t)v.w;
        }
    } else {
        *(bf16x8*)dst = *(const bf16x8*)src;
    }
}

__device__ inline void pk_atomic_add_bf16(bf16_t* addr, float lo, float hi)
{
#if __has_builtin(__builtin_amdgcn_global_atomic_fadd_v2bf16)
    union { bf16_t b[2]; v2s s; } pk;
    pk.b[0] = (bf16_t)lo;
    pk.b[1] = (bf16_t)hi;
    (void)__builtin_amdgcn_global_atomic_fadd_v2bf16((v2s*)addr, pk.s);
#else
    unsigned int* w = (unsigned int*)addr;
    unsigned int old = __hip_atomic_load(w, __ATOMIC_RELAXED, __HIP_MEMORY_SCOPE_AGENT);
    while (true) {
        union { unsigned int u; bf16_t b[2]; } cur;
        cur.u = old;
        cur.b[0] = (bf16_t)((float)cur.b[0] + lo);
        cur.b[1] = (bf16_t)((float)cur.b[1] + hi);
        unsigned int prev = atomicCAS(w, old, cur.u);
        if (prev == old) break;
        old = prev;
    }
#endif
}

// ---- sort pass 1: per-block histogram via wave ballots (no atomics) ----
__global__ __launch_bounds__(256) void bin_hist_kernel(
    const void* __restrict__ ei, int* __restrict__ bcnt, const int* __restrict__ flags)
{
    const int i64 = flags[1];
    __shared__ int sCnt[4][8];
    const int tid = threadIdx.x;
    const int w = tid >> 6;
    const int lane = tid & 63;
    size_t e = (size_t)blockIdx.x * 256 + tid;
    int row = min(max(load_idx(ei, i64, e), 0), NN - 1);
    int b = (row * 8) / NN;
#pragma unroll
    for (int bb = 0; bb < 8; ++bb) {
        unsigned long long mask = __ballot(b == bb);
        if (lane == 0) sCnt[w][bb] = (int)__popcll(mask);
    }
    __syncthreads();
    if (tid < 8)
        bcnt[(size_t)tid * NBLK_SORT + blockIdx.x] =
            sCnt[0][tid] + sCnt[1][tid] + sCnt[2][tid] + sCnt[3][tid];
}

// ---- sort pass 2: exclusive scan of bin-major counts (single block) ----
__global__ __launch_bounds__(256) void bin_scan_kernel(
    const int* __restrict__ bcnt, int* __restrict__ boff)
{
    __shared__ int chunk[256];
    const int tid = threadIdx.x;
    const int C = (SCAN_TOTAL + 255) / 256;   // 98
    const int lo = tid * C;
    const int hi = min(lo + C, SCAN_TOTAL);
    int s = 0;
    for (int i = lo; i < hi; ++i) s += bcnt[i];
    chunk[tid] = s;
    __syncthreads();
    if (tid == 0) {
        int run = 0;
        for (int i = 0; i < 256; ++i) { int v = chunk[i]; chunk[i] = run; run += v; }
    }
    __syncthreads();
    int run = chunk[tid];
    for (int i = lo; i < hi; ++i) { boff[i] = run; run += bcnt[i]; }
}

// ---- sort pass 3: deterministic scatter (ballot rank + LDS wave prefix) ----
__global__ __launch_bounds__(256) void bin_scatter2_kernel(
    const void* __restrict__ ei, const int* __restrict__ boff,
    int* __restrict__ perm, int* __restrict__ rowS, int* __restrict__ colS,
    const int* __restrict__ flags)
{
    const int i64 = flags[1];
    __shared__ int sCnt[4][8];
    __shared__ int sBase[4][8];
    const int tid = threadIdx.x;
    const int w = tid >> 6;
    const int lane = tid & 63;
    size_t e = (size_t)blockIdx.x * 256 + tid;
    int row = min(max(load_idx(ei, i64, e), 0), NN - 1);
    int col = min(max(load_idx(ei, i64, (size_t)EE + e), 0), NN - 1);
    int b = (row * 8) / NN;
    int rank = 0;
#pragma unroll
    for (int bb = 0; bb < 8; ++bb) {
        unsigned long long mask = __ballot(b == bb);
        if (lane == 0) sCnt[w][bb] = (int)__popcll(mask);
        if (b == bb) rank = (int)__popcll(mask & ((1ull << lane) - 1ull));
    }
    __syncthreads();
    if (tid < 8) {
        int run = 0;
#pragma unroll
        for (int ww = 0; ww < 4; ++ww) { sBase[ww][tid] = run; run += sCnt[ww][tid]; }
    }
    __syncthreads();
    int pos = boff[(size_t)b * NBLK_SORT + blockIdx.x] + sBase[w][b] + rank;
    perm[pos] = (int)e;
    rowS[pos] = row;
    colS[pos] = col;
}

// ---- prep: transpose weights -> bf16 ws; biases -> float ws ----
template <typename FT>
__global__ __launch_bounds__(256) void prep_kernel(
    const FT* __restrict__ eW1, const FT* __restrict__ eW2,
    const FT* __restrict__ nW1, const FT* __restrict__ nW2,
    const FT* __restrict__ b1, const FT* __restrict__ b2,
    const FT* __restrict__ nb1, const FT* __restrict__ nb2,
    bf16_t* __restrict__ W1t, bf16_t* __restrict__ W2t,
    bf16_t* __restrict__ nW1t, bf16_t* __restrict__ nW2t,
    float* __restrict__ biasF, const int* __restrict__ flags)
{
    constexpr int WANT = std::is_same<FT, float>::value ? 1 : 0;
    if (flags[0] != WANT) return;
    int idx = blockIdx.x * 256 + threadIdx.x;
    if (idx < 128 * 288) {
        int n = idx / 288;
        int k = idx - n * 288;
        W1t[idx] = (k < 272) ? (bf16_t)(float)eW1[k * 128 + n] : (bf16_t)0.0f;
    } else if (idx < 128 * 288 + 128 * 128) {
        int j = idx - 128 * 288;
        int n = j >> 7, k = j & 127;
        W2t[j] = (bf16_t)(float)eW2[k * 128 + n];
    } else if (idx < 128 * 288 + 128 * 128 + 128 * 256) {
        int j = idx - (128 * 288 + 128 * 128);
        int n = j >> 8, k = j & 255;
        nW1t[j] = (bf16_t)(float)nW1[k * 128 + n];
    } else if (idx < 102400) {
        int j = idx - (128 * 288 + 128 * 128 + 128 * 256);
        int n = j >> 7, k = j & 127;
        nW2t[j] = (bf16_t)(float)nW2[k * 128 + n];
    } else if (idx < 102912) {
        int j = idx - 102400;
        int which = j >> 7, c = j & 127;
        const FT* src = which == 0 ? b1 : which == 1 ? b2 : which == 2 ? nb1 : nb2;
        biasF[j] = (float)src[c];
    }
}

// ---- conv_x: x (FT) -> xb (bf16) ----
template <typename FT>
__global__ __launch_bounds__(256) void conv_x_kernel(
    const FT* __restrict__ x, bf16_t* __restrict__ xb,
    const int* __restrict__ flags)
{
    constexpr int WANT = std::is_same<FT, float>::value ? 1 : 0;
    if (flags[0] != WANT) return;
    size_t i = ((size_t)blockIdx.x * 256 + threadIdx.x) * 8;
    if (i >= (size_t)NN * DD) return;
    bf16x8 v;
    if constexpr (std::is_same<FT, float>::value) {
        float4 a = *(const float4*)(x + i);
        float4 b = *(const float4*)(x + i + 4);
        v[0] = (bf16_t)a.x; v[1] = (bf16_t)a.y; v[2] = (bf16_t)a.z; v[3] = (bf16_t)a.w;
        v[4] = (bf16_t)b.x; v[5] = (bf16_t)b.y; v[6] = (bf16_t)b.z; v[7] = (bf16_t)b.w;
    } else {
        v = *(const bf16x8*)(x + i);
    }
    *(bf16x8*)(xb + i) = v;
}

// ---- pq: P = xb @ eW1[0:128], Q = xb @ eW1[128:256] (both bf16 to ws) ----
__global__ __launch_bounds__(256) void pq_kernel(
    const bf16_t* __restrict__ xb, const bf16_t* __restrict__ W1t,
    bf16_t* __restrict__ P, bf16_t* __restrict__ Q)
{
    __shared__ bf16_t sX[64 * PH];
    __shared__ bf16_t sB[128 * PB];
    const int tid = threadIdx.x;
    const int n0 = blockIdx.x * 64;

    {
        const int m = tid >> 2;
        const int part = tid & 3;
        int n = n0 + m;
        if (n >= NN) n = NN - 1;
        const bf16x8* src = (const bf16x8*)(xb + (size_t)n * DD + part * 32);
        bf16x8* dst = (bf16x8*)&sX[m * PH + part * 32];
#pragma unroll
        for (int i = 0; i < 4; ++i) dst[i] = src[i];
    }

    const int lane = tid & 63;
    const int wv = tid >> 6;
    const int ml = lane & 15;
    const int q = lane >> 4;
    const int m0 = wv * 16;
    const floatx4 fzero = {0.f, 0.f, 0.f, 0.f};

    for (int pass = 0; pass < 2; ++pass) {
        floatx4 acc[8];
#pragma unroll
        for (int i = 0; i < 8; ++i) acc[i] = fzero;

        for (int kc = 0; kc < 4; ++kc) {
            __syncthreads();
            {
                const int n = tid >> 1;
                const int half = tid & 1;
                const bf16x8* src = (const bf16x8*)(W1t + n * 288 + pass * 128 + kc * 32 + half * 16);
                bf16x8* dst = (bf16x8*)&sB[n * PB + half * 16];
                dst[0] = src[0];
                dst[1] = src[1];
            }
            __syncthreads();
            const bf16x8 a = *(const bf16x8*)&sX[(m0 + ml) * PH + kc * 32 + q * 8];
#pragma unroll
            for (int nt = 0; nt < 8; ++nt) {
                const bf16x8 b = *(const bf16x8*)&sB[(nt * 16 + ml) * PB + q * 8];
                acc[nt] = __builtin_amdgcn_mfma_f32_16x16x32_bf16(a, b, acc[nt], 0, 0, 0);
            }
        }

        bf16_t* dst = pass ? Q : P;
#pragma unroll
        for (int r = 0; r < 4; ++r) {
            const int n = n0 + m0 + q * 4 + r;
#pragma unroll
            for (int nt = 0; nt < 8; ++nt) {
                float v = acc[nt][r];
                const float pv = __shfl_xor(v, 1, 64);
                if (((lane & 1) == 0) && n < NN) {
                    union { bf16_t b[2]; unsigned int u; } pk;
                    pk.b[0] = (bf16_t)v;
                    pk.b[1] = (bf16_t)pv;
                    *(unsigned int*)(dst + (size_t)n * DD + nt * 16 + ml) = pk.u;
                }
            }
        }
    }
}

// ======== edge v5: v3 structure + binned edge order + XCD-pinned bins ========
// Block b processes tiles of bin (b%8) only => with round-robin block->XCD
// dispatch, all agg atomics (and P-row gathers) of XCD i hit a 1.6 MB slice
// resident in its private L2. Correctness independent of the mapping.
__global__ __launch_bounds__(256) void edge_kernel_v5(
    const int* __restrict__ perm, const int* __restrict__ rowS,
    const int* __restrict__ colS, const void* __restrict__ ea,
    const bf16_t* __restrict__ P, const bf16_t* __restrict__ Q,
    const bf16_t* __restrict__ W1t, const bf16_t* __restrict__ W2t,
    const float* __restrict__ biasF, const int* __restrict__ boff,
    bf16_t* __restrict__ agg, const int* __restrict__ flags)
{
    const int f32 = flags[0];

    __shared__ bf16_t sH[64 * PH];    // P+Q sum, then h (layer-2 A operand)
    __shared__ bf16_t sEA[64 * 32];   // ea tile, k 16..31 zero
    __shared__ bf16_t sB[128 * PB];   // B staging: ea-chunk of W1t, then W2 chunks
    __shared__ int    sIdx[64];       // clamped dest row per edge

    const int tid = threadIdx.x;
    const int bin  = blockIdx.x & 7;
    const int rank = blockIdx.x >> 3;
    const int nb   = gridDim.x >> 3;
    const int binS = boff[(size_t)bin * NBLK_SORT];
    const int binE = (bin == 7) ? EE : boff[(size_t)(bin + 1) * NBLK_SORT];
    const int tLo  = (binS + 63) >> 6;
    const int tHi  = (binE + 63) >> 6;

    const int lane = tid & 63;
    const int wv = tid >> 6;
    const int ml = lane & 15;
    const int q = lane >> 4;
    const int m0 = wv * 16;
    const floatx4 fzero = {0.f, 0.f, 0.f, 0.f};

    for (int t = tLo + rank; t < tHi; t += nb) {
        // ---- stage: sH = bf16(P[row]+Q[col]); sEA; sB = W1t ea-chunk ----
        {
            const int m = tid >> 2;
            const int part = tid & 3;
            const int epos = t * 64 + m;
            const int rn = rowS[epos];
            const int cn = colS[epos];
            if (part == 0) sIdx[m] = rn;
            const bf16x8* pr = (const bf16x8*)(P + (size_t)rn * DD + part * 32);
            const bf16x8* qc = (const bf16x8*)(Q + (size_t)cn * DD + part * 32);
#pragma unroll
            for (int i = 0; i < 4; ++i) {
                bf16x8 a = pr[i], b = qc[i], o;
#pragma unroll
                for (int j = 0; j < 8; ++j) o[j] = (bf16_t)((float)a[j] + (float)b[j]);
                *(bf16x8*)&sH[m * PH + part * 32 + i * 8] = o;
            }
            if (part < 2) {
                const int ep = perm[epos];
                if (f32) cp8<float>(&sEA[m * 32 + part * 8], (const float*)ea + (size_t)ep * 16 + part * 8);
                else     cp8<bf16_t>(&sEA[m * 32 + part * 8], (const bf16_t*)ea + (size_t)ep * 16 + part * 8);
            } else {
                *(float4*)&sEA[m * 32 + part * 8] = make_float4(0.f, 0.f, 0.f, 0.f);
            }
            {
                const int n = tid >> 1;
                const int half = tid & 1;
                const bf16x8* src = (const bf16x8*)(W1t + n * 288 + 256 + half * 16);
                bf16x8* dst = (bf16x8*)&sB[n * PB + half * 16];
                dst[0] = src[0];
                dst[1] = src[1];
            }
        }
        __syncthreads();

        // ---- ea contribution: one K=32 MFMA chunk ----
        floatx4 acc[8];
        {
            const bf16x8 a = *(const bf16x8*)&sEA[(m0 + ml) * 32 + q * 8];
#pragma unroll
            for (int nt = 0; nt < 8; ++nt) {
                const bf16x8 b = *(const bf16x8*)&sB[(nt * 16 + ml) * PB + q * 8];
                acc[nt] = __builtin_amdgcn_mfma_f32_16x16x32_bf16(a, b, fzero, 0, 0, 0);
            }
        }

        // ---- h = silu(acc + (P+Q) + b1), in place (wave-local rows) ----
#pragma unroll
        for (int nt = 0; nt < 8; ++nt) {
            const float bias = biasF[nt * 16 + ml];
#pragma unroll
            for (int r = 0; r < 4; ++r) {
                const int row = m0 + q * 4 + r;
                const int col = nt * 16 + ml;
                float v = acc[nt][r] + bias + (float)sH[row * PH + col];
                sH[row * PH + col] = (bf16_t)fast_silu(v);
            }
        }

        floatx4 acc2[8];
#pragma unroll
        for (int i = 0; i < 8; ++i) acc2[i] = fzero;

        // ---- layer 2: [64x128] @ [128x128], 4 K-chunks ----
        for (int kc = 0; kc < 4; ++kc) {
            __syncthreads();
            {
                const int n = tid >> 1;
                const int half = tid & 1;
                const bf16x8* src = (const bf16x8*)(W2t + n * 128 + kc * 32 + half * 16);
                bf16x8* dst = (bf16x8*)&sB[n * PB + half * 16];
                dst[0] = src[0];
                dst[1] = src[1];
            }
            __syncthreads();
            const bf16x8 a = *(const bf16x8*)&sH[(m0 + ml) * PH + kc * 32 + q * 8];
#pragma unroll
            for (int nt = 0; nt < 8; ++nt) {
                const bf16x8 b = *(const bf16x8*)&sB[(nt * 16 + ml) * PB + q * 8];
                acc2[nt] = __builtin_amdgcn_mfma_f32_16x16x32_bf16(a, b, acc2[nt], 0, 0, 0);
            }
        }

        // ---- m_ij = silu(acc2 + b2); pk-bf16 scatter (L2-local rows) ----
#pragma unroll
        for (int r = 0; r < 4; ++r) {
            const int rs = sIdx[m0 + q * 4 + r];
            bf16_t* base = agg + (size_t)rs * DD;
#pragma unroll
            for (int nt = 0; nt < 8; ++nt) {
                float v = fast_silu(acc2[nt][r] + biasF[128 + nt * 16 + ml]);
                const float pv = __shfl_xor(v, 1, 64);
                if ((ml & 1) == 0)
                    pk_atomic_add_bf16(base + nt * 16 + ml, v, pv);
            }
        }
        __syncthreads();   // sB/sH reused next iteration (cross-wave readers)
    }
}

// ======== edge v3 (fallback: ws fits P/Q but not binning arrays) ========
__global__ __launch_bounds__(256) void edge_kernel_v3(
    const void* __restrict__ ei, const void* __restrict__ ea,
    const bf16_t* __restrict__ P, const bf16_t* __restrict__ Q,
    const bf16_t* __restrict__ W1t, const bf16_t* __restrict__ W2t,
    const float* __restrict__ biasF,
    bf16_t* __restrict__ agg, const int* __restrict__ flags)
{
    const int f32 = flags[0];
    const int i64 = flags[1];

    __shared__ bf16_t sH[64 * PH];
    __shared__ bf16_t sEA[64 * 32];
    __shared__ bf16_t sB[128 * PB];
    const int tid = threadIdx.x;
    const int e0 = blockIdx.x * 64;

    {
        const int m = tid >> 2;
        const int part = tid & 3;
        const int e = e0 + m;
        int rn = load_idx(ei, i64, e);
        int cn = load_idx(ei, i64, (size_t)EE + e);
        rn = min(max(rn, 0), NN - 1);
        cn = min(max(cn, 0), NN - 1);
        const bf16x8* pr = (const bf16x8*)(P + (size_t)rn * DD + part * 32);
        const bf16x8* qc = (const bf16x8*)(Q + (size_t)cn * DD + part * 32);
#pragma unroll
        for (int i = 0; i < 4; ++i) {
            bf16x8 a = pr[i], b = qc[i], o;
#pragma unroll
            for (int j = 0; j < 8; ++j) o[j] = (bf16_t)((float)a[j] + (float)b[j]);
            *(bf16x8*)&sH[m * PH + part * 32 + i * 8] = o;
        }
        if (part < 2) {
            if (f32) cp8<float>(&sEA[m * 32 + part * 8], (const float*)ea + (size_t)e * 16 + part * 8);
            else     cp8<bf16_t>(&sEA[m * 32 + part * 8], (const bf16_t*)ea + (size_t)e * 16 + part * 8);
        } else {
            *(float4*)&sEA[m * 32 + part * 8] = make_float4(0.f, 0.f, 0.f, 0.f);
        }
        {
            const int n = tid >> 1;
            const int half = tid & 1;
            const bf16x8* src = (const bf16x8*)(W1t + n * 288 + 256 + half * 16);
            bf16x8* dst = (bf16x8*)&sB[n * PB + half * 16];
            dst[0] = src[0];
            dst[1] = src[1];
        }
    }
    __syncthreads();

    const int lane = tid & 63;
    const int wv = tid >> 6;
    const int ml = lane & 15;
    const int q = lane >> 4;
    const int m0 = wv * 16;
    const floatx4 fzero = {0.f, 0.f, 0.f, 0.f};

    floatx4 acc[8];
#pragma unroll
    for (int i = 0; i < 8; ++i) acc[i] = fzero;
    {
        const bf16x8 a = *(const bf16x8*)&sEA[(m0 + ml) * 32 + q * 8];
#pragma unroll
        for (int nt = 0; nt < 8; ++nt) {
            const bf16x8 b = *(const bf16x8*)&sB[(nt * 16 + ml) * PB + q * 8];
            acc[nt] = __builtin_amdgcn_mfma_f32_16x16x32_bf16(a, b, acc[nt], 0, 0, 0);
        }
    }

#pragma unroll
    for (int nt = 0; nt < 8; ++nt) {
        const float bias = biasF[nt * 16 + ml];
#pragma unroll
        for (int r = 0; r < 4; ++r) {
            const int row = m0 + q * 4 + r;
            const int col = nt * 16 + ml;
            float v = acc[nt][r] + bias + (float)sH[row * PH + col];
            sH[row * PH + col] = (bf16_t)fast_silu(v);
        }
    }

    floatx4 acc2[8];
#pragma unroll
    for (int i = 0; i < 8; ++i) acc2[i] = fzero;

    for (int kc = 0; kc < 4; ++kc) {
        __syncthreads();
        {
            const int n = tid >> 1;
            const int half = tid & 1;
            const bf16x8* src = (const bf16x8*)(W2t + n * 128 + kc * 32 + half * 16);
            bf16x8* dst = (bf16x8*)&sB[n * PB + half * 16];
            dst[0] = src[0];
            dst[1] = src[1];
        }
        __syncthreads();
        const bf16x8 a = *(const bf16x8*)&sH[(m0 + ml) * PH + kc * 32 + q * 8];
#pragma unroll
        for (int nt = 0; nt < 8; ++nt) {
            const bf16x8 b = *(const bf16x8*)&sB[(nt * 16 + ml) * PB + q * 8];
            acc2[nt] = __builtin_amdgcn_mfma_f32_16x16x32_bf16(a, b, acc2[nt], 0, 0, 0);
        }
    }

#pragma unroll
    for (int r = 0; r < 4; ++r) {
        const int e = e0 + m0 + q * 4 + r;
        int rn = load_idx(ei, i64, e);
        rn = min(max(rn, 0), NN - 1);
#pragma unroll
        for (int nt = 0; nt < 8; ++nt) {
            float v = fast_silu(acc2[nt][r] + biasF[128 + nt * 16 + ml]);
            const float pv = __shfl_xor(v, 1, 64);
            if ((ml & 1) == 0)
                pk_atomic_add_bf16(agg + (size_t)rn * DD + nt * 16 + ml, v, pv);
        }
    }
}

// ======== edge v2 (fallback if ws too small for P/Q) ========
__global__ __launch_bounds__(256) void edge_kernel_v2(
    const bf16_t* __restrict__ xb, const void* __restrict__ ei,
    const void* __restrict__ ea,
    const bf16_t* __restrict__ W1t, const bf16_t* __restrict__ W2t,
    const float* __restrict__ biasF,
    bf16_t* __restrict__ agg, const int* __restrict__ flags)
{
    const int f32 = flags[0];
    const int i64 = flags[1];

    __shared__ bf16_t sA[64 * PA];
    __shared__ bf16_t sB[128 * PB];
    const int tid = threadIdx.x;
    const int e0 = blockIdx.x * 64;

    {
        const int m = tid >> 2;
        const int part = tid & 3;
        const int e = e0 + m;
        int rn = load_idx(ei, i64, e);
        int cn = load_idx(ei, i64, (size_t)EE + e);
        rn = min(max(rn, 0), NN - 1);
        cn = min(max(cn, 0), NN - 1);
        const bf16x8* xr = (const bf16x8*)(xb + (size_t)rn * DD + part * 32);
        const bf16x8* xc = (const bf16x8*)(xb + (size_t)cn * DD + part * 32);
        bf16x8* dR = (bf16x8*)&sA[m * PA + part * 32];
        bf16x8* dC = (bf16x8*)&sA[m * PA + 128 + part * 32];
#pragma unroll
        for (int i = 0; i < 4; ++i) dR[i] = xr[i];
#pragma unroll
        for (int i = 0; i < 4; ++i) dC[i] = xc[i];
        if (part < 2) {
            if (f32) cp8<float>(&sA[m * PA + 256 + part * 8], (const float*)ea + (size_t)e * 16 + part * 8);
            else     cp8<bf16_t>(&sA[m * PA + 256 + part * 8], (const bf16_t*)ea + (size_t)e * 16 + part * 8);
        } else {
            *(float4*)&sA[m * PA + 256 + part * 8] = make_float4(0.f, 0.f, 0.f, 0.f);
        }
    }

    const int lane = tid & 63;
    const int wv = tid >> 6;
    const int ml = lane & 15;
    const int q = lane >> 4;
    const int m0 = wv * 16;

    const floatx4 fzero = {0.f, 0.f, 0.f, 0.f};
    floatx4 acc[8];
#pragma unroll
    for (int i = 0; i < 8; ++i) acc[i] = fzero;

    for (int kc = 0; kc < 9; ++kc) {
        __syncthreads();
        {
            const int n = tid >> 1;
            const int half = tid & 1;
            const bf16x8* src = (const bf16x8*)(W1t + n * 288 + kc * 32 + half * 16);
            bf16x8* dst = (bf16x8*)&sB[n * PB + half * 16];
            dst[0] = src[0];
            dst[1] = src[1];
        }
        __syncthreads();
        const bf16x8 a = *(const bf16x8*)&sA[(m0 + ml) * PA + kc * 32 + q * 8];
#pragma unroll
        for (int nt = 0; nt < 8; ++nt) {
            const bf16x8 b = *(const bf16x8*)&sB[(nt * 16 + ml) * PB + q * 8];
            acc[nt] = __builtin_amdgcn_mfma_f32_16x16x32_bf16(a, b, acc[nt], 0, 0, 0);
        }
    }

#pragma unroll
    for (int nt = 0; nt < 8; ++nt) {
        const float bias = biasF[nt * 16 + ml];
#pragma unroll
        for (int r = 0; r < 4; ++r) {
            float v = acc[nt][r] + bias;
            sA[(m0 + q * 4 + r) * PA + nt * 16 + ml] = (bf16_t)fast_silu(v);
        }
    }
    __syncthreads();

    floatx4 acc2[8];
#pragma unroll
    for (int i = 0; i < 8; ++i) acc2[i] = fzero;

    for (int kc = 0; kc < 4; ++kc) {
        __syncthreads();
        {
            const int n = tid >> 1;
            const int half = tid & 1;
            const bf16x8* src = (const bf16x8*)(W2t + n * 128 + kc * 32 + half * 16);
            bf16x8* dst = (bf16x8*)&sB[n * PB + half * 16];
            dst[0] = src[0];
            dst[1] = src[1];
        }
        __syncthreads();
        const bf16x8 a = *(const bf16x8*)&sA[(m0 + ml) * PA + kc * 32 + q * 8];
#pragma unroll
        for (int nt = 0; nt < 8; ++nt) {
            const bf16x8 b = *(const bf16x8*)&sB[(nt * 16 + ml) * PB + q * 8];
            acc2[nt] = __builtin_amdgcn_mfma_f32_16x16x32_bf16(a, b, acc2[nt], 0, 0, 0);
        }
    }

    float bias2[8];
#pragma unroll
    for (int nt = 0; nt < 8; ++nt) bias2[nt] = biasF[128 + nt * 16 + ml];
#pragma unroll
    for (int r = 0; r < 4; ++r) {
        const int e = e0 + m0 + q * 4 + r;
        int rn = load_idx(ei, i64, e);
        rn = min(max(rn, 0), NN - 1);
#pragma unroll
        for (int nt = 0; nt < 8; ++nt) {
            float v = fast_silu(acc2[nt][r] + bias2[nt]);
            const float pv = __shfl_xor(v, 1, 64);
            if ((ml & 1) == 0)
                pk_atomic_add_bf16(agg + (size_t)rn * DD + nt * 16 + ml, v, pv);
        }
    }
}

// -------- node MLP: out = x + (silu([xb|agg] @ nW1 + nb1) @ nW2 + nb2) --------
template <typename FT>
__global__ __launch_bounds__(256) void node_kernel_v2(
    const FT* __restrict__ x, const bf16_t* __restrict__ xb,
    const bf16_t* __restrict__ agg,
    const bf16_t* __restrict__ nW1t, const bf16_t* __restrict__ nW2t,
    const float* __restrict__ biasF,
    FT* __restrict__ out, const int* __restrict__ flags)
{
    constexpr int WANT = std::is_same<FT, float>::value ? 1 : 0;
    if (flags[0] != WANT) return;

    __shared__ bf16_t sA[64 * PN];
    __shared__ bf16_t sB[128 * PB];
    const int tid = threadIdx.x;
    const int n0 = blockIdx.x * 64;

    {
        const int m = tid >> 2;
        const int p = tid & 3;
        int n = n0 + m;
        if (n >= NN) n = NN - 1;
        const bf16_t* srcbase = (p < 2) ? xb : agg;
        const int col = (p & 1) * 64;
        const bf16x8* src = (const bf16x8*)(srcbase + (size_t)n * DD + col);
        bf16x8* dst = (bf16x8*)&sA[m * PN + (p >> 1) * 128 + col];
#pragma unroll
        for (int i = 0; i < 8; ++i) dst[i] = src[i];
    }

    const int lane = tid & 63;
    const int wv = tid >> 6;
    const int ml = lane & 15;
    const int q = lane >> 4;
    const int m0 = wv * 16;

    const floatx4 fzero = {0.f, 0.f, 0.f, 0.f};
    floatx4 acc[8];
#pragma unroll
    for (int i = 0; i < 8; ++i) acc[i] = fzero;

    for (int kc = 0; kc < 8; ++kc) {
        __syncthreads();
        {
            const int n = tid >> 1;
            const int half = tid & 1;
            const bf16x8* src = (const bf16x8*)(nW1t + n * 256 + kc * 32 + half * 16);
            bf16x8* dst = (bf16x8*)&sB[n * PB + half * 16];
            dst[0] = src[0];
            dst[1] = src[1];
        }
        __syncthreads();
        const bf16x8 a = *(const bf16x8*)&sA[(m0 + ml) * PN + kc * 32 + q * 8];
#pragma unroll
        for (int nt = 0; nt < 8; ++nt) {
            const bf16x8 b = *(const bf16x8*)&sB[(nt * 16 + ml) * PB + q * 8];
            acc[nt] = __builtin_amdgcn_mfma_f32_16x16x32_bf16(a, b, acc[nt], 0, 0, 0);
        }
    }

#pragma unroll
    for (int nt = 0; nt < 8; ++nt) {
        const float bias = biasF[256 + nt * 16 + ml];
#pragma unroll
        for (int r = 0; r < 4; ++r) {
            float v = acc[nt][r] + bias;
            sA[(m0 + q * 4 + r) * PN + nt * 16 + ml] = (bf16_t)fast_silu(v);
        }
    }
    __syncthreads();

    floatx4 acc2[8];
#pragma unroll
    for (int i = 0; i < 8; ++i) acc2[i] = fzero;

    for (int kc = 0; kc < 4; ++kc) {
        __syncthreads();
        {
            const int n = tid >> 1;
            const int half = tid & 1;
            const bf16x8* src = (const bf16x8*)(nW2t + n * 128 + kc * 32 + half * 16);
            bf16x8* dst = (bf16x8*)&sB[n * PB + half * 16];
            dst[0] = src[0];
            dst[1] = src[1];
        }
        __syncthreads();
        const bf16x8 a = *(const bf16x8*)&sA[(m0 + ml) * PN + kc * 32 + q * 8];
#pragma unroll
        for (int nt = 0; nt < 8; ++nt) {
            const bf16x8 b = *(const bf16x8*)&sB[(nt * 16 + ml) * PB + q * 8];
            acc2[nt] = __builtin_amdgcn_mfma_f32_16x16x32_bf16(a, b, acc2[nt], 0, 0, 0);
        }
    }

#pragma unroll
    for (int r = 0; r < 4; ++r) {
        const int n = n0 + m0 + q * 4 + r;
        if (n < NN) {
#pragma unroll
            for (int nt = 0; nt < 8; ++nt) {
                const int col = nt * 16 + ml;
                float v = acc2[nt][r] + biasF[384 + col];
                float xv = (float)x[(size_t)n * DD + col];
                out[(size_t)n * DD + col] = (FT)(xv + v);
            }
        }
    }
}

extern "C" void kernel_launch(void* const* d_in, const int* in_sizes, int n_in,
                              void* d_out, int out_size, void* d_ws, size_t ws_size,
                              hipStream_t stream)
{
    const void* x   = d_in[0];
    const void* ei  = d_in[1];
    const void* ea  = d_in[2];
    const void* eW1 = d_in[3];
    const void* eb1 = d_in[4];
    const void* eW2 = d_in[5];
    const void* eb2 = d_in[6];
    const void* nW1 = d_in[7];
    const void* nb1 = d_in[8];
    const void* nW2 = d_in[9];
    const void* nb2 = d_in[10];

    char* ws = (char*)d_ws;
    int*    flags = (int*)ws;
    bf16_t* W1t   = (bf16_t*)(ws + W1T_OFF);
    bf16_t* W2t   = (bf16_t*)(ws + W2T_OFF);
    bf16_t* nW1t  = (bf16_t*)(ws + NW1T_OFF);
    bf16_t* nW2t  = (bf16_t*)(ws + NW2T_OFF);
    float*  biasF = (float*)(ws + BIASF_OFF);
    bf16_t* xb    = (bf16_t*)(ws + XB_OFF);
    bf16_t* agg   = (bf16_t*)(ws + AGG_OFF);
    bf16_t* P     = (bf16_t*)(ws + P_OFF);
    bf16_t* Q     = (bf16_t*)(ws + Q_OFF);
    int*    perm  = (int*)(ws + PERM_OFF);
    int*    rowS  = (int*)(ws + ROWS_OFF);
    int*    colS  = (int*)(ws + COLS_OFF);
    int*    bcnt  = (int*)(ws + BCNT_OFF);
    int*    boff  = (int*)(ws + BOFF_OFF);

    detect_kernel<<<1, 1, 0, stream>>>((const unsigned short*)x,
                                       (const unsigned int*)ei, flags);

    prep_kernel<bf16_t><<<403, 256, 0, stream>>>(
        (const bf16_t*)eW1, (const bf16_t*)eW2, (const bf16_t*)nW1, (const bf16_t*)nW2,
        (const bf16_t*)eb1, (const bf16_t*)eb2, (const bf16_t*)nb1, (const bf16_t*)nb2,
        W1t, W2t, nW1t, nW2t, biasF, flags);
    prep_kernel<float><<<403, 256, 0, stream>>>(
        (const float*)eW1, (const float*)eW2, (const float*)nW1, (const float*)nW2,
        (const float*)eb1, (const float*)eb2, (const float*)nb1, (const float*)nb2,
        W1t, W2t, nW1t, nW2t, biasF, flags);

    (void)hipMemsetAsync(agg, 0, AGG_BYTES, stream);
    conv_x_kernel<bf16_t><<<3125, 256, 0, stream>>>((const bf16_t*)x, xb, flags);
    conv_x_kernel<float><<<3125, 256, 0, stream>>>((const float*)x, xb, flags);

    if (ws_size >= WS_V5) {
        bin_hist_kernel<<<NBLK_SORT, 256, 0, stream>>>(ei, bcnt, flags);
        bin_scan_kernel<<<1, 256, 0, stream>>>(bcnt, boff);
        bin_scatter2_kernel<<<NBLK_SORT, 256, 0, stream>>>(ei, boff, perm, rowS, colS, flags);
        pq_kernel<<<(NN + 63) / 64, 256, 0, stream>>>(xb, W1t, P, Q);
        edge_kernel_v5<<<12504, 256, 0, stream>>>(perm, rowS, colS, ea, P, Q,
                                                  W1t, W2t, biasF, boff, agg, flags);
    } else if (ws_size >= WS_V3) {
        pq_kernel<<<(NN + 63) / 64, 256, 0, stream>>>(xb, W1t, P, Q);
        edge_kernel_v3<<<EE / 64, 256, 0, stream>>>(ei, ea, P, Q, W1t, W2t, biasF, agg, flags);
    } else {
        edge_kernel_v2<<<EE / 64, 256, 0, stream>>>(xb, ei, ea, W1t, W2t, biasF, agg, flags);
    }

    node_kernel_v2<bf16_t><<<(NN + 63) / 64, 256, 0, stream>>>(
        (const bf16_t*)x, xb, agg, nW1t, nW2t, biasF, (bf16_t*)d_out, flags);
    node_kernel_v2<float><<<(NN + 63) / 64, 256, 0, stream>>>(
        (const float*)x, xb, agg, nW1t, nW2t, biasF, (float*)d_out, flags);
}

// Round 5
// 514.583 us; speedup vs baseline: 5.5310x; 1.2073x over previous
//
#include <hip/hip_runtime.h>
#include <hip/hip_bf16.h>
#include <type_traits>

typedef __bf16 bf16_t;
typedef __bf16 bf16x8 __attribute__((ext_vector_type(8)));
typedef float floatx4 __attribute__((ext_vector_type(4)));
typedef short v2s __attribute__((ext_vector_type(2)));

#define NN 50000
#define EE 800000
#define DD 128

// ---- ws layout (bytes) ----
#define W1T_OFF   256                                  // [128][288] (K 272->288 zero-pad)
#define W2T_OFF   (W1T_OFF + (size_t)128 * 288 * 2)    // [128][128]
#define NW1T_OFF  (W2T_OFF + (size_t)128 * 128 * 2)    // [128][256]
#define NW2T_OFF  (NW1T_OFF + (size_t)128 * 256 * 2)   // [128][128]
#define BIASF_OFF (NW2T_OFF + (size_t)128 * 128 * 2)   // float[512]: b1|b2|nb1|nb2
#define XB_OFF    207360                               // bf16 x copy [NN][DD]
#define AGG_OFF   (XB_OFF + (size_t)NN * DD * 2)       // bf16 agg [NN][DD]
#define AGG_BYTES ((size_t)NN * DD * 2)
#define WS_V2     (AGG_OFF + AGG_BYTES)                // 25,807,360 (proven available)
#define P_OFF     WS_V2                                // bf16 P = x @ eW1[0:128]
#define Q_OFF     (P_OFF + (size_t)NN * DD * 2)        // bf16 Q = x @ eW1[128:256]
#define WS_V3     (Q_OFF + (size_t)NN * DD * 2)        // 51,407,360 (proven available)
// v6: FULL counting sort of edges by destination row -> in-tile segment merge
#define PERM_OFF   WS_V3                               // int[EE] original edge id, sorted
#define ROWS_OFF   (PERM_OFF + (size_t)EE * 4)         // int[EE] clamped row, sorted (ascending)
#define COLS_OFF   (ROWS_OFF + (size_t)EE * 4)         // int[EE] clamped col, sorted order
#define RSTART_OFF (COLS_OFF + (size_t)EE * 4)         // int[NN+1] row segment starts
#define RCNT_OFF   (RSTART_OFF + (size_t)(NN + 256) * 4) // int[NN] histogram
#define ROFS_OFF   (RCNT_OFF + (size_t)NN * 4)         // int[NN] scatter cursors
#define WS_V6      (ROFS_OFF + (size_t)NN * 4)         // ~61.6 MB

#define NTILES (EE / 64)      // 12500 exact

// LDS pitches (bf16 elems)
#define PA 304   // v2 edge A pitch
#define PB 48    // B chunk pitch (32 + 16 pad)
#define PN 272   // node A pitch (256 + 16 pad)
#define PH 136   // h/x pitch (128 + 8 pad; 272B rows, 16B-aligned)

// ---- dtype-detect ----
__global__ void detect_kernel(const unsigned short* __restrict__ xraw,
                              const unsigned int* __restrict__ eiraw,
                              int* __restrict__ flags)
{
    int cnt = 0;
    for (int i = 0; i < 64; ++i) {
        unsigned short u = xraw[2 * i];
        int ex = (u >> 7) & 0xFF;
        if (ex >= 100 && ex <= 140) cnt++;
    }
    flags[0] = (cnt < 32) ? 1 : 0;   // 1 => fp32
    int zc = 0;
    for (int i = 0; i < 32; ++i)
        if (eiraw[2 * i + 1] == 0u) zc++;
    flags[1] = (zc >= 16) ? 1 : 0;   // 1 => int64
}

__device__ inline int load_idx(const void* ei, int i64, size_t pos)
{
    return i64 ? (int)((const long long*)ei)[pos] : ((const int*)ei)[pos];
}

// silu via v_rcp_f32: avoids the exact-div sequence; error << bf16 rounding.
__device__ inline float fast_silu(float v)
{
    float e = __expf(-v);
    return v * __builtin_amdgcn_rcpf(1.0f + e);
}

template <typename FT>
__device__ inline void cp8(bf16_t* dst, const FT* src)
{
    if constexpr (std::is_same<FT, float>::value) {
#pragma unroll
        for (int i = 0; i < 8; i += 4) {
            float4 v = *(const float4*)(src + i);
            dst[i + 0] = (bf16_t)v.x; dst[i + 1] = (bf16_t)v.y;
            dst[i + 2] = (bf16_t)v.z; dst[i + 3] = (bf16_t)v.w;
        }
    } else {
        *(bf16x8*)dst = *(const bf16x8*)src;
    }
}

__device__ inline void pk_atomic_add_bf16(bf16_t* addr, float lo, float hi)
{
#if __has_builtin(__builtin_amdgcn_global_atomic_fadd_v2bf16)
    union { bf16_t b[2]; v2s s; } pk;
    pk.b[0] = (bf16_t)lo;
    pk.b[1] = (bf16_t)hi;
    (void)__builtin_amdgcn_global_atomic_fadd_v2bf16((v2s*)addr, pk.s);
#else
    unsigned int* w = (unsigned int*)addr;
    unsigned int old = __hip_atomic_load(w, __ATOMIC_RELAXED, __HIP_MEMORY_SCOPE_AGENT);
    while (true) {
        union { unsigned int u; bf16_t b[2]; } cur;
        cur.u = old;
        cur.b[0] = (bf16_t)((float)cur.b[0] + lo);
        cur.b[1] = (bf16_t)((float)cur.b[1] + hi);
        unsigned int prev = atomicCAS(w, old, cur.u);
        if (prev == old) break;
        old = prev;
    }
#endif
}

// ---- sort pass 1: 50K-bin histogram, fire-and-forget atomics (spread lines) ----
__global__ __launch_bounds__(256) void row_hist_kernel(
    const void* __restrict__ ei, int* __restrict__ rcnt, const int* __restrict__ flags)
{
    const int i64 = flags[1];
    size_t e = (size_t)blockIdx.x * 256 + threadIdx.x;
    int row = min(max(load_idx(ei, i64, e), 0), NN - 1);
    atomicAdd(&rcnt[row], 1);
}

// ---- sort pass 2: exclusive scan of 50K counts (single block, chunked) ----
__global__ __launch_bounds__(256) void row_scan_kernel(
    const int* __restrict__ rcnt, int* __restrict__ rstart)
{
    __shared__ int chunk[256];
    const int tid = threadIdx.x;
    const int C = (NN + 255) / 256;   // 196
    const int lo = tid * C;
    const int hi = min(lo + C, NN);
    int s = 0;
    for (int i = lo; i < hi; ++i) s += rcnt[i];
    chunk[tid] = s;
    __syncthreads();
    if (tid == 0) {
        int run = 0;
        for (int i = 0; i < 256; ++i) { int v = chunk[i]; chunk[i] = run; run += v; }
    }
    __syncthreads();
    int run = chunk[tid];
    for (int i = lo; i < hi; ++i) { rstart[i] = run; run += rcnt[i]; }
    if (tid == 255) rstart[NN] = run;   // == EE
}

// ---- sort pass 3: scatter via one returning atomic per edge (50K spread cursors) ----
__global__ __launch_bounds__(256) void row_scatter_kernel(
    const void* __restrict__ ei, const int* __restrict__ rstart,
    int* __restrict__ rofs,
    int* __restrict__ perm, int* __restrict__ rowS, int* __restrict__ colS,
    const int* __restrict__ flags)
{
    const int i64 = flags[1];
    size_t e = (size_t)blockIdx.x * 256 + threadIdx.x;
    int row = min(max(load_idx(ei, i64, e), 0), NN - 1);
    int col = min(max(load_idx(ei, i64, (size_t)EE + e), 0), NN - 1);
    int pos = rstart[row] + atomicAdd(&rofs[row], 1);
    perm[pos] = (int)e;
    rowS[pos] = row;
    colS[pos] = col;
}

// ---- prep: transpose weights -> bf16 ws; biases -> float ws ----
template <typename FT>
__global__ __launch_bounds__(256) void prep_kernel(
    const FT* __restrict__ eW1, const FT* __restrict__ eW2,
    const FT* __restrict__ nW1, const FT* __restrict__ nW2,
    const FT* __restrict__ b1, const FT* __restrict__ b2,
    const FT* __restrict__ nb1, const FT* __restrict__ nb2,
    bf16_t* __restrict__ W1t, bf16_t* __restrict__ W2t,
    bf16_t* __restrict__ nW1t, bf16_t* __restrict__ nW2t,
    float* __restrict__ biasF, const int* __restrict__ flags)
{
    constexpr int WANT = std::is_same<FT, float>::value ? 1 : 0;
    if (flags[0] != WANT) return;
    int idx = blockIdx.x * 256 + threadIdx.x;
    if (idx < 128 * 288) {
        int n = idx / 288;
        int k = idx - n * 288;
        W1t[idx] = (k < 272) ? (bf16_t)(float)eW1[k * 128 + n] : (bf16_t)0.0f;
    } else if (idx < 128 * 288 + 128 * 128) {
        int j = idx - 128 * 288;
        int n = j >> 7, k = j & 127;
        W2t[j] = (bf16_t)(float)eW2[k * 128 + n];
    } else if (idx < 128 * 288 + 128 * 128 + 128 * 256) {
        int j = idx - (128 * 288 + 128 * 128);
        int n = j >> 8, k = j & 255;
        nW1t[j] = (bf16_t)(float)nW1[k * 128 + n];
    } else if (idx < 102400) {
        int j = idx - (128 * 288 + 128 * 128 + 128 * 256);
        int n = j >> 7, k = j & 127;
        nW2t[j] = (bf16_t)(float)nW2[k * 128 + n];
    } else if (idx < 102912) {
        int j = idx - 102400;
        int which = j >> 7, c = j & 127;
        const FT* src = which == 0 ? b1 : which == 1 ? b2 : which == 2 ? nb1 : nb2;
        biasF[j] = (float)src[c];
    }
}

// ---- conv_x: x (FT) -> xb (bf16) ----
template <typename FT>
__global__ __launch_bounds__(256) void conv_x_kernel(
    const FT* __restrict__ x, bf16_t* __restrict__ xb,
    const int* __restrict__ flags)
{
    constexpr int WANT = std::is_same<FT, float>::value ? 1 : 0;
    if (flags[0] != WANT) return;
    size_t i = ((size_t)blockIdx.x * 256 + threadIdx.x) * 8;
    if (i >= (size_t)NN * DD) return;
    bf16x8 v;
    if constexpr (std::is_same<FT, float>::value) {
        float4 a = *(const float4*)(x + i);
        float4 b = *(const float4*)(x + i + 4);
        v[0] = (bf16_t)a.x; v[1] = (bf16_t)a.y; v[2] = (bf16_t)a.z; v[3] = (bf16_t)a.w;
        v[4] = (bf16_t)b.x; v[5] = (bf16_t)b.y; v[6] = (bf16_t)b.z; v[7] = (bf16_t)b.w;
    } else {
        v = *(const bf16x8*)(x + i);
    }
    *(bf16x8*)(xb + i) = v;
}

// ---- pq: P = xb @ eW1[0:128], Q = xb @ eW1[128:256] (both bf16 to ws) ----
__global__ __launch_bounds__(256) void pq_kernel(
    const bf16_t* __restrict__ xb, const bf16_t* __restrict__ W1t,
    bf16_t* __restrict__ P, bf16_t* __restrict__ Q)
{
    __shared__ bf16_t sX[64 * PH];
    __shared__ bf16_t sB[128 * PB];
    const int tid = threadIdx.x;
    const int n0 = blockIdx.x * 64;

    {
        const int m = tid >> 2;
        const int part = tid & 3;
        int n = n0 + m;
        if (n >= NN) n = NN - 1;
        const bf16x8* src = (const bf16x8*)(xb + (size_t)n * DD + part * 32);
        bf16x8* dst = (bf16x8*)&sX[m * PH + part * 32];
#pragma unroll
        for (int i = 0; i < 4; ++i) dst[i] = src[i];
    }

    const int lane = tid & 63;
    const int wv = tid >> 6;
    const int ml = lane & 15;
    const int q = lane >> 4;
    const int m0 = wv * 16;
    const floatx4 fzero = {0.f, 0.f, 0.f, 0.f};

    for (int pass = 0; pass < 2; ++pass) {
        floatx4 acc[8];
#pragma unroll
        for (int i = 0; i < 8; ++i) acc[i] = fzero;

        for (int kc = 0; kc < 4; ++kc) {
            __syncthreads();
            {
                const int n = tid >> 1;
                const int half = tid & 1;
                const bf16x8* src = (const bf16x8*)(W1t + n * 288 + pass * 128 + kc * 32 + half * 16);
                bf16x8* dst = (bf16x8*)&sB[n * PB + half * 16];
                dst[0] = src[0];
                dst[1] = src[1];
            }
            __syncthreads();
            const bf16x8 a = *(const bf16x8*)&sX[(m0 + ml) * PH + kc * 32 + q * 8];
#pragma unroll
            for (int nt = 0; nt < 8; ++nt) {
                const bf16x8 b = *(const bf16x8*)&sB[(nt * 16 + ml) * PB + q * 8];
                acc[nt] = __builtin_amdgcn_mfma_f32_16x16x32_bf16(a, b, acc[nt], 0, 0, 0);
            }
        }

        bf16_t* dst = pass ? Q : P;
#pragma unroll
        for (int r = 0; r < 4; ++r) {
            const int n = n0 + m0 + q * 4 + r;
#pragma unroll
            for (int nt = 0; nt < 8; ++nt) {
                float v = acc[nt][r];
                const float pv = __shfl_xor(v, 1, 64);
                if (((lane & 1) == 0) && n < NN) {
                    union { bf16_t b[2]; unsigned int u; } pk;
                    pk.b[0] = (bf16_t)v;
                    pk.b[1] = (bf16_t)pv;
                    *(unsigned int*)(dst + (size_t)n * DD + nt * 16 + ml) = pk.u;
                }
            }
        }
    }
}

// ======== edge v6: row-sorted edges + in-tile segment merge (8x fewer atomics) ====
// Edges sorted by destination row. Per wave (16 edges), lane owns one col-pair;
// a wave-uniform scan over sIdx sums same-row edges in f32 and emits ONE
// coalesced packed-bf16 atomic per (segment, col-pair).
__global__ __launch_bounds__(256) void edge_kernel_v6(
    const int* __restrict__ perm, const int* __restrict__ rowS,
    const int* __restrict__ colS, const void* __restrict__ ea,
    const bf16_t* __restrict__ P, const bf16_t* __restrict__ Q,
    const bf16_t* __restrict__ W1t, const bf16_t* __restrict__ W2t,
    const float* __restrict__ biasF,
    bf16_t* __restrict__ agg, const int* __restrict__ flags)
{
    const int f32 = flags[0];

    __shared__ bf16_t sH[64 * PH];    // P+Q sum -> h -> m (all wave-private rows)
    __shared__ bf16_t sEA[64 * 32];   // ea tile, k 16..31 zero
    __shared__ bf16_t sB[128 * PB];   // B staging: W1t ea-chunk, then W2 chunks
    __shared__ int    sIdx[64];       // sorted dest row per edge

    const int tid = threadIdx.x;
    const int t = blockIdx.x;         // one 64-edge tile per block

    // ---- stage: sH = bf16(P[row]+Q[col]); sEA; sB = W1t ea-chunk ----
    {
        const int m = tid >> 2;
        const int part = tid & 3;
        const int epos = t * 64 + m;
        const int rn = rowS[epos];
        const int cn = colS[epos];
        if (part == 0) sIdx[m] = rn;
        const bf16x8* pr = (const bf16x8*)(P + (size_t)rn * DD + part * 32);
        const bf16x8* qc = (const bf16x8*)(Q + (size_t)cn * DD + part * 32);
#pragma unroll
        for (int i = 0; i < 4; ++i) {
            bf16x8 a = pr[i], b = qc[i], o;
#pragma unroll
            for (int j = 0; j < 8; ++j) o[j] = (bf16_t)((float)a[j] + (float)b[j]);
            *(bf16x8*)&sH[m * PH + part * 32 + i * 8] = o;
        }
        if (part < 2) {
            const int ep = perm[epos];
            if (f32) cp8<float>(&sEA[m * 32 + part * 8], (const float*)ea + (size_t)ep * 16 + part * 8);
            else     cp8<bf16_t>(&sEA[m * 32 + part * 8], (const bf16_t*)ea + (size_t)ep * 16 + part * 8);
        } else {
            *(float4*)&sEA[m * 32 + part * 8] = make_float4(0.f, 0.f, 0.f, 0.f);
        }
        {
            const int n = tid >> 1;
            const int half = tid & 1;
            const bf16x8* src = (const bf16x8*)(W1t + n * 288 + 256 + half * 16);
            bf16x8* dst = (bf16x8*)&sB[n * PB + half * 16];
            dst[0] = src[0];
            dst[1] = src[1];
        }
    }
    __syncthreads();

    const int lane = tid & 63;
    const int wv = tid >> 6;
    const int ml = lane & 15;
    const int q = lane >> 4;
    const int m0 = wv * 16;
    const floatx4 fzero = {0.f, 0.f, 0.f, 0.f};

    // ---- ea contribution: one K=32 MFMA chunk ----
    floatx4 acc[8];
    {
        const bf16x8 a = *(const bf16x8*)&sEA[(m0 + ml) * 32 + q * 8];
#pragma unroll
        for (int nt = 0; nt < 8; ++nt) {
            const bf16x8 b = *(const bf16x8*)&sB[(nt * 16 + ml) * PB + q * 8];
            acc[nt] = __builtin_amdgcn_mfma_f32_16x16x32_bf16(a, b, fzero, 0, 0, 0);
        }
    }

    // ---- h = silu(acc + (P+Q) + b1), in place (wave-local rows) ----
#pragma unroll
    for (int nt = 0; nt < 8; ++nt) {
        const float bias = biasF[nt * 16 + ml];
#pragma unroll
        for (int r = 0; r < 4; ++r) {
            const int row = m0 + q * 4 + r;
            const int col = nt * 16 + ml;
            float v = acc[nt][r] + bias + (float)sH[row * PH + col];
            sH[row * PH + col] = (bf16_t)fast_silu(v);
        }
    }

    floatx4 acc2[8];
#pragma unroll
    for (int i = 0; i < 8; ++i) acc2[i] = fzero;

    // ---- layer 2: [64x128] @ [128x128], 4 K-chunks ----
    for (int kc = 0; kc < 4; ++kc) {
        __syncthreads();
        {
            const int n = tid >> 1;
            const int half = tid & 1;
            const bf16x8* src = (const bf16x8*)(W2t + n * 128 + kc * 32 + half * 16);
            bf16x8* dst = (bf16x8*)&sB[n * PB + half * 16];
            dst[0] = src[0];
            dst[1] = src[1];
        }
        __syncthreads();
        const bf16x8 a = *(const bf16x8*)&sH[(m0 + ml) * PH + kc * 32 + q * 8];
#pragma unroll
        for (int nt = 0; nt < 8; ++nt) {
            const bf16x8 b = *(const bf16x8*)&sB[(nt * 16 + ml) * PB + q * 8];
            acc2[nt] = __builtin_amdgcn_mfma_f32_16x16x32_bf16(a, b, acc2[nt], 0, 0, 0);
        }
    }

    // ---- m = silu(acc2 + b2) -> sH (wave-private rows; h dead now) ----
#pragma unroll
    for (int r = 0; r < 4; ++r) {
#pragma unroll
        for (int nt = 0; nt < 8; ++nt) {
            float v = fast_silu(acc2[nt][r] + biasF[128 + nt * 16 + ml]);
            const float pv = __shfl_xor(v, 1, 64);
            if ((ml & 1) == 0) {
                union { bf16_t b[2]; unsigned int u; } pk;
                pk.b[0] = (bf16_t)v;
                pk.b[1] = (bf16_t)pv;
                *(unsigned int*)&sH[(m0 + q * 4 + r) * PH + nt * 16 + ml] = pk.u;
            }
        }
    }

    // ---- wave-local segment reduce over sorted rows; one atomic per segment ----
    // lane owns col-pair `lane` (cols 2*lane, 2*lane+1); branch is wave-uniform.
    {
        float lo = 0.f, hi = 0.f;
        int curRow = sIdx[m0];
#pragma unroll
        for (int i = 0; i < 16; ++i) {
            const int r = sIdx[m0 + i];
            if (r != curRow) {
                pk_atomic_add_bf16(agg + (size_t)curRow * DD + lane * 2, lo, hi);
                lo = 0.f; hi = 0.f;
                curRow = r;
            }
            union { unsigned int u; bf16_t b[2]; } pk;
            pk.u = *(const unsigned int*)&sH[(m0 + i) * PH + lane * 2];
            lo += (float)pk.b[0];
            hi += (float)pk.b[1];
        }
        pk_atomic_add_bf16(agg + (size_t)curRow * DD + lane * 2, lo, hi);
    }
}

// ======== edge v3 (fallback: ws fits P/Q but not sort arrays) ========
__global__ __launch_bounds__(256) void edge_kernel_v3(
    const void* __restrict__ ei, const void* __restrict__ ea,
    const bf16_t* __restrict__ P, const bf16_t* __restrict__ Q,
    const bf16_t* __restrict__ W1t, const bf16_t* __restrict__ W2t,
    const float* __restrict__ biasF,
    bf16_t* __restrict__ agg, const int* __restrict__ flags)
{
    const int f32 = flags[0];
    const int i64 = flags[1];

    __shared__ bf16_t sH[64 * PH];
    __shared__ bf16_t sEA[64 * 32];
    __shared__ bf16_t sB[128 * PB];
    const int tid = threadIdx.x;
    const int e0 = blockIdx.x * 64;

    {
        const int m = tid >> 2;
        const int part = tid & 3;
        const int e = e0 + m;
        int rn = load_idx(ei, i64, e);
        int cn = load_idx(ei, i64, (size_t)EE + e);
        rn = min(max(rn, 0), NN - 1);
        cn = min(max(cn, 0), NN - 1);
        const bf16x8* pr = (const bf16x8*)(P + (size_t)rn * DD + part * 32);
        const bf16x8* qc = (const bf16x8*)(Q + (size_t)cn * DD + part * 32);
#pragma unroll
        for (int i = 0; i < 4; ++i) {
            bf16x8 a = pr[i], b = qc[i], o;
#pragma unroll
            for (int j = 0; j < 8; ++j) o[j] = (bf16_t)((float)a[j] + (float)b[j]);
            *(bf16x8*)&sH[m * PH + part * 32 + i * 8] = o;
        }
        if (part < 2) {
            if (f32) cp8<float>(&sEA[m * 32 + part * 8], (const float*)ea + (size_t)e * 16 + part * 8);
            else     cp8<bf16_t>(&sEA[m * 32 + part * 8], (const bf16_t*)ea + (size_t)e * 16 + part * 8);
        } else {
            *(float4*)&sEA[m * 32 + part * 8] = make_float4(0.f, 0.f, 0.f, 0.f);
        }
        {
            const int n = tid >> 1;
            const int half = tid & 1;
            const bf16x8* src = (const bf16x8*)(W1t + n * 288 + 256 + half * 16);
            bf16x8* dst = (bf16x8*)&sB[n * PB + half * 16];
            dst[0] = src[0];
            dst[1] = src[1];
        }
    }
    __syncthreads();

    const int lane = tid & 63;
    const int wv = tid >> 6;
    const int ml = lane & 15;
    const int q = lane >> 4;
    const int m0 = wv * 16;
    const floatx4 fzero = {0.f, 0.f, 0.f, 0.f};

    floatx4 acc[8];
#pragma unroll
    for (int i = 0; i < 8; ++i) acc[i] = fzero;
    {
        const bf16x8 a = *(const bf16x8*)&sEA[(m0 + ml) * 32 + q * 8];
#pragma unroll
        for (int nt = 0; nt < 8; ++nt) {
            const bf16x8 b = *(const bf16x8*)&sB[(nt * 16 + ml) * PB + q * 8];
            acc[nt] = __builtin_amdgcn_mfma_f32_16x16x32_bf16(a, b, acc[nt], 0, 0, 0);
        }
    }

#pragma unroll
    for (int nt = 0; nt < 8; ++nt) {
        const float bias = biasF[nt * 16 + ml];
#pragma unroll
        for (int r = 0; r < 4; ++r) {
            const int row = m0 + q * 4 + r;
            const int col = nt * 16 + ml;
            float v = acc[nt][r] + bias + (float)sH[row * PH + col];
            sH[row * PH + col] = (bf16_t)fast_silu(v);
        }
    }

    floatx4 acc2[8];
#pragma unroll
    for (int i = 0; i < 8; ++i) acc2[i] = fzero;

    for (int kc = 0; kc < 4; ++kc) {
        __syncthreads();
        {
            const int n = tid >> 1;
            const int half = tid & 1;
            const bf16x8* src = (const bf16x8*)(W2t + n * 128 + kc * 32 + half * 16);
            bf16x8* dst = (bf16x8*)&sB[n * PB + half * 16];
            dst[0] = src[0];
            dst[1] = src[1];
        }
        __syncthreads();
        const bf16x8 a = *(const bf16x8*)&sH[(m0 + ml) * PH + kc * 32 + q * 8];
#pragma unroll
        for (int nt = 0; nt < 8; ++nt) {
            const bf16x8 b = *(const bf16x8*)&sB[(nt * 16 + ml) * PB + q * 8];
            acc2[nt] = __builtin_amdgcn_mfma_f32_16x16x32_bf16(a, b, acc2[nt], 0, 0, 0);
        }
    }

#pragma unroll
    for (int r = 0; r < 4; ++r) {
        const int e = e0 + m0 + q * 4 + r;
        int rn = load_idx(ei, i64, e);
        rn = min(max(rn, 0), NN - 1);
#pragma unroll
        for (int nt = 0; nt < 8; ++nt) {
            float v = fast_silu(acc2[nt][r] + biasF[128 + nt * 16 + ml]);
            const float pv = __shfl_xor(v, 1, 64);
            if ((ml & 1) == 0)
                pk_atomic_add_bf16(agg + (size_t)rn * DD + nt * 16 + ml, v, pv);
        }
    }
}

// ======== edge v2 (fallback if ws too small for P/Q) ========
__global__ __launch_bounds__(256) void edge_kernel_v2(
    const bf16_t* __restrict__ xb, const void* __restrict__ ei,
    const void* __restrict__ ea,
    const bf16_t* __restrict__ W1t, const bf16_t* __restrict__ W2t,
    const float* __restrict__ biasF,
    bf16_t* __restrict__ agg, const int* __restrict__ flags)
{
    const int f32 = flags[0];
    const int i64 = flags[1];

    __shared__ bf16_t sA[64 * PA];
    __shared__ bf16_t sB[128 * PB];
    const int tid = threadIdx.x;
    const int e0 = blockIdx.x * 64;

    {
        const int m = tid >> 2;
        const int part = tid & 3;
        const int e = e0 + m;
        int rn = load_idx(ei, i64, e);
        int cn = load_idx(ei, i64, (size_t)EE + e);
        rn = min(max(rn, 0), NN - 1);
        cn = min(max(cn, 0), NN - 1);
        const bf16x8* xr = (const bf16x8*)(xb + (size_t)rn * DD + part * 32);
        const bf16x8* xc = (const bf16x8*)(xb + (size_t)cn * DD + part * 32);
        bf16x8* dR = (bf16x8*)&sA[m * PA + part * 32];
        bf16x8* dC = (bf16x8*)&sA[m * PA + 128 + part * 32];
#pragma unroll
        for (int i = 0; i < 4; ++i) dR[i] = xr[i];
#pragma unroll
        for (int i = 0; i < 4; ++i) dC[i] = xc[i];
        if (part < 2) {
            if (f32) cp8<float>(&sA[m * PA + 256 + part * 8], (const float*)ea + (size_t)e * 16 + part * 8);
            else     cp8<bf16_t>(&sA[m * PA + 256 + part * 8], (const bf16_t*)ea + (size_t)e * 16 + part * 8);
        } else {
            *(float4*)&sA[m * PA + 256 + part * 8] = make_float4(0.f, 0.f, 0.f, 0.f);
        }
    }

    const int lane = tid & 63;
    const int wv = tid >> 6;
    const int ml = lane & 15;
    const int q = lane >> 4;
    const int m0 = wv * 16;

    const floatx4 fzero = {0.f, 0.f, 0.f, 0.f};
    floatx4 acc[8];
#pragma unroll
    for (int i = 0; i < 8; ++i) acc[i] = fzero;

    for (int kc = 0; kc < 9; ++kc) {
        __syncthreads();
        {
            const int n = tid >> 1;
            const int half = tid & 1;
            const bf16x8* src = (const bf16x8*)(W1t + n * 288 + kc * 32 + half * 16);
            bf16x8* dst = (bf16x8*)&sB[n * PB + half * 16];
            dst[0] = src[0];
            dst[1] = src[1];
        }
        __syncthreads();
        const bf16x8 a = *(const bf16x8*)&sA[(m0 + ml) * PA + kc * 32 + q * 8];
#pragma unroll
        for (int nt = 0; nt < 8; ++nt) {
            const bf16x8 b = *(const bf16x8*)&sB[(nt * 16 + ml) * PB + q * 8];
            acc[nt] = __builtin_amdgcn_mfma_f32_16x16x32_bf16(a, b, acc[nt], 0, 0, 0);
        }
    }

#pragma unroll
    for (int nt = 0; nt < 8; ++nt) {
        const float bias = biasF[nt * 16 + ml];
#pragma unroll
        for (int r = 0; r < 4; ++r) {
            float v = acc[nt][r] + bias;
            sA[(m0 + q * 4 + r) * PA + nt * 16 + ml] = (bf16_t)fast_silu(v);
        }
    }
    __syncthreads();

    floatx4 acc2[8];
#pragma unroll
    for (int i = 0; i < 8; ++i) acc2[i] = fzero;

    for (int kc = 0; kc < 4; ++kc) {
        __syncthreads();
        {
            const int n = tid >> 1;
            const int half = tid & 1;
            const bf16x8* src = (const bf16x8*)(W2t + n * 128 + kc * 32 + half * 16);
            bf16x8* dst = (bf16x8*)&sB[n * PB + half * 16];
            dst[0] = src[0];
            dst[1] = src[1];
        }
        __syncthreads();
        const bf16x8 a = *(const bf16x8*)&sA[(m0 + ml) * PA + kc * 32 + q * 8];
#pragma unroll
        for (int nt = 0; nt < 8; ++nt) {
            const bf16x8 b = *(const bf16x8*)&sB[(nt * 16 + ml) * PB + q * 8];
            acc2[nt] = __builtin_amdgcn_mfma_f32_16x16x32_bf16(a, b, acc2[nt], 0, 0, 0);
        }
    }

    float bias2[8];
#pragma unroll
    for (int nt = 0; nt < 8; ++nt) bias2[nt] = biasF[128 + nt * 16 + ml];
#pragma unroll
    for (int r = 0; r < 4; ++r) {
        const int e = e0 + m0 + q * 4 + r;
        int rn = load_idx(ei, i64, e);
        rn = min(max(rn, 0), NN - 1);
#pragma unroll
        for (int nt = 0; nt < 8; ++nt) {
            float v = fast_silu(acc2[nt][r] + bias2[nt]);
            const float pv = __shfl_xor(v, 1, 64);
            if ((ml & 1) == 0)
                pk_atomic_add_bf16(agg + (size_t)rn * DD + nt * 16 + ml, v, pv);
        }
    }
}

// -------- node MLP: out = x + (silu([xb|agg] @ nW1 + nb1) @ nW2 + nb2) --------
template <typename FT>
__global__ __launch_bounds__(256) void node_kernel_v2(
    const FT* __restrict__ x, const bf16_t* __restrict__ xb,
    const bf16_t* __restrict__ agg,
    const bf16_t* __restrict__ nW1t, const bf16_t* __restrict__ nW2t,
    const float* __restrict__ biasF,
    FT* __restrict__ out, const int* __restrict__ flags)
{
    constexpr int WANT = std::is_same<FT, float>::value ? 1 : 0;
    if (flags[0] != WANT) return;

    __shared__ bf16_t sA[64 * PN];
    __shared__ bf16_t sB[128 * PB];
    const int tid = threadIdx.x;
    const int n0 = blockIdx.x * 64;

    {
        const int m = tid >> 2;
        const int p = tid & 3;
        int n = n0 + m;
        if (n >= NN) n = NN - 1;
        const bf16_t* srcbase = (p < 2) ? xb : agg;
        const int col = (p & 1) * 64;
        const bf16x8* src = (const bf16x8*)(srcbase + (size_t)n * DD + col);
        bf16x8* dst = (bf16x8*)&sA[m * PN + (p >> 1) * 128 + col];
#pragma unroll
        for (int i = 0; i < 8; ++i) dst[i] = src[i];
    }

    const int lane = tid & 63;
    const int wv = tid >> 6;
    const int ml = lane & 15;
    const int q = lane >> 4;
    const int m0 = wv * 16;

    const floatx4 fzero = {0.f, 0.f, 0.f, 0.f};
    floatx4 acc[8];
#pragma unroll
    for (int i = 0; i < 8; ++i) acc[i] = fzero;

    for (int kc = 0; kc < 8; ++kc) {
        __syncthreads();
        {
            const int n = tid >> 1;
            const int half = tid & 1;
            const bf16x8* src = (const bf16x8*)(nW1t + n * 256 + kc * 32 + half * 16);
            bf16x8* dst = (bf16x8*)&sB[n * PB + half * 16];
            dst[0] = src[0];
            dst[1] = src[1];
        }
        __syncthreads();
        const bf16x8 a = *(const bf16x8*)&sA[(m0 + ml) * PN + kc * 32 + q * 8];
#pragma unroll
        for (int nt = 0; nt < 8; ++nt) {
            const bf16x8 b = *(const bf16x8*)&sB[(nt * 16 + ml) * PB + q * 8];
            acc[nt] = __builtin_amdgcn_mfma_f32_16x16x32_bf16(a, b, acc[nt], 0, 0, 0);
        }
    }

#pragma unroll
    for (int nt = 0; nt < 8; ++nt) {
        const float bias = biasF[256 + nt * 16 + ml];
#pragma unroll
        for (int r = 0; r < 4; ++r) {
            float v = acc[nt][r] + bias;
            sA[(m0 + q * 4 + r) * PN + nt * 16 + ml] = (bf16_t)fast_silu(v);
        }
    }
    __syncthreads();

    floatx4 acc2[8];
#pragma unroll
    for (int i = 0; i < 8; ++i) acc2[i] = fzero;

    for (int kc = 0; kc < 4; ++kc) {
        __syncthreads();
        {
            const int n = tid >> 1;
            const int half = tid & 1;
            const bf16x8* src = (const bf16x8*)(nW2t + n * 128 + kc * 32 + half * 16);
            bf16x8* dst = (bf16x8*)&sB[n * PB + half * 16];
            dst[0] = src[0];
            dst[1] = src[1];
        }
        __syncthreads();
        const bf16x8 a = *(const bf16x8*)&sA[(m0 + ml) * PN + kc * 32 + q * 8];
#pragma unroll
        for (int nt = 0; nt < 8; ++nt) {
            const bf16x8 b = *(const bf16x8*)&sB[(nt * 16 + ml) * PB + q * 8];
            acc2[nt] = __builtin_amdgcn_mfma_f32_16x16x32_bf16(a, b, acc2[nt], 0, 0, 0);
        }
    }

#pragma unroll
    for (int r = 0; r < 4; ++r) {
        const int n = n0 + m0 + q * 4 + r;
        if (n < NN) {
#pragma unroll
            for (int nt = 0; nt < 8; ++nt) {
                const int col = nt * 16 + ml;
                float v = acc2[nt][r] + biasF[384 + col];
                float xv = (float)x[(size_t)n * DD + col];
                out[(size_t)n * DD + col] = (FT)(xv + v);
            }
        }
    }
}

extern "C" void kernel_launch(void* const* d_in, const int* in_sizes, int n_in,
                              void* d_out, int out_size, void* d_ws, size_t ws_size,
                              hipStream_t stream)
{
    const void* x   = d_in[0];
    const void* ei  = d_in[1];
    const void* ea  = d_in[2];
    const void* eW1 = d_in[3];
    const void* eb1 = d_in[4];
    const void* eW2 = d_in[5];
    const void* eb2 = d_in[6];
    const void* nW1 = d_in[7];
    const void* nb1 = d_in[8];
    const void* nW2 = d_in[9];
    const void* nb2 = d_in[10];

    char* ws = (char*)d_ws;
    int*    flags  = (int*)ws;
    bf16_t* W1t    = (bf16_t*)(ws + W1T_OFF);
    bf16_t* W2t    = (bf16_t*)(ws + W2T_OFF);
    bf16_t* nW1t   = (bf16_t*)(ws + NW1T_OFF);
    bf16_t* nW2t   = (bf16_t*)(ws + NW2T_OFF);
    float*  biasF  = (float*)(ws + BIASF_OFF);
    bf16_t* xb     = (bf16_t*)(ws + XB_OFF);
    bf16_t* agg    = (bf16_t*)(ws + AGG_OFF);
    bf16_t* P      = (bf16_t*)(ws + P_OFF);
    bf16_t* Q      = (bf16_t*)(ws + Q_OFF);
    int*    perm   = (int*)(ws + PERM_OFF);
    int*    rowS   = (int*)(ws + ROWS_OFF);
    int*    colS   = (int*)(ws + COLS_OFF);
    int*    rstart = (int*)(ws + RSTART_OFF);
    int*    rcnt   = (int*)(ws + RCNT_OFF);
    int*    rofs   = (int*)(ws + ROFS_OFF);

    detect_kernel<<<1, 1, 0, stream>>>((const unsigned short*)x,
                                       (const unsigned int*)ei, flags);

    prep_kernel<bf16_t><<<403, 256, 0, stream>>>(
        (const bf16_t*)eW1, (const bf16_t*)eW2, (const bf16_t*)nW1, (const bf16_t*)nW2,
        (const bf16_t*)eb1, (const bf16_t*)eb2, (const bf16_t*)nb1, (const bf16_t*)nb2,
        W1t, W2t, nW1t, nW2t, biasF, flags);
    prep_kernel<float><<<403, 256, 0, stream>>>(
        (const float*)eW1, (const float*)eW2, (const float*)nW1, (const float*)nW2,
        (const float*)eb1, (const float*)eb2, (const float*)nb1, (const float*)nb2,
        W1t, W2t, nW1t, nW2t, biasF, flags);

    (void)hipMemsetAsync(agg, 0, AGG_BYTES, stream);
    conv_x_kernel<bf16_t><<<3125, 256, 0, stream>>>((const bf16_t*)x, xb, flags);
    conv_x_kernel<float><<<3125, 256, 0, stream>>>((const float*)x, xb, flags);

    if (ws_size >= WS_V6) {
        (void)hipMemsetAsync(rcnt, 0, (size_t)2 * NN * 4, stream);   // rcnt + rofs contiguous
        row_hist_kernel<<<EE / 256, 256, 0, stream>>>(ei, rcnt, flags);
        row_scan_kernel<<<1, 256, 0, stream>>>(rcnt, rstart);
        row_scatter_kernel<<<EE / 256, 256, 0, stream>>>(ei, rstart, rofs,
                                                         perm, rowS, colS, flags);
        pq_kernel<<<(NN + 63) / 64, 256, 0, stream>>>(xb, W1t, P, Q);
        edge_kernel_v6<<<NTILES, 256, 0, stream>>>(perm, rowS, colS, ea, P, Q,
                                                   W1t, W2t, biasF, agg, flags);
    } else if (ws_size >= WS_V3) {
        pq_kernel<<<(NN + 63) / 64, 256, 0, stream>>>(xb, W1t, P, Q);
        edge_kernel_v3<<<EE / 64, 256, 0, stream>>>(ei, ea, P, Q, W1t, W2t, biasF, agg, flags);
    } else {
        edge_kernel_v2<<<EE / 64, 256, 0, stream>>>(xb, ei, ea, W1t, W2t, biasF, agg, flags);
    }

    node_kernel_v2<bf16_t><<<(NN + 63) / 64, 256, 0, stream>>>(
        (const bf16_t*)x, xb, agg, nW1t, nW2t, biasF, (bf16_t*)d_out, flags);
    node_kernel_v2<float><<<(NN + 63) / 64, 256, 0, stream>>>(
        (const float*)x, xb, agg, nW1t, nW2t, biasF, (float*)d_out, flags);
}

// Round 6
// 512.141 us; speedup vs baseline: 5.5574x; 1.0048x over previous
//
#include <hip/hip_runtime.h>
#include <hip/hip_bf16.h>
#include <type_traits>

typedef __bf16 bf16_t;
typedef __bf16 bf16x8 __attribute__((ext_vector_type(8)));
typedef float floatx4 __attribute__((ext_vector_type(4)));
typedef short v2s __attribute__((ext_vector_type(2)));

#define NN 50000
#define EE 800000
#define DD 128

// ---- ws layout (bytes) ----
#define W1T_OFF   256                                  // [128][288] (K 272->288 zero-pad)
#define W2T_OFF   (W1T_OFF + (size_t)128 * 288 * 2)    // [128][128]
#define NW1T_OFF  (W2T_OFF + (size_t)128 * 128 * 2)    // [128][256]
#define NW2T_OFF  (NW1T_OFF + (size_t)128 * 256 * 2)   // [128][128]
#define BIASF_OFF (NW2T_OFF + (size_t)128 * 128 * 2)   // float[512]: b1|b2|nb1|nb2
#define XB_OFF    207360                               // bf16 x copy [NN][DD]
#define AGG_OFF   (XB_OFF + (size_t)NN * DD * 2)       // bf16 agg [NN][DD]
#define AGG_BYTES ((size_t)NN * DD * 2)
#define WS_V2     (AGG_OFF + AGG_BYTES)                // 25,807,360 (proven available)
#define P_OFF     WS_V2                                // bf16 P = x @ eW1[0:128]
#define Q_OFF     (P_OFF + (size_t)NN * DD * 2)        // bf16 Q = x @ eW1[128:256]
#define WS_V3     (Q_OFF + (size_t)NN * DD * 2)        // 51,407,360 (proven available)
// v6: FULL counting sort of edges by destination row -> in-tile segment merge.
// Packed payload: one uint2 per edge = {row | col<<16, perm} (single 8B store).
#define EPK_OFF    WS_V3                               // uint2[EE] packed (row,col,perm)
#define RSTART_OFF (EPK_OFF + (size_t)EE * 8)          // int[NN+1] row segment starts
#define RCNT_OFF   (RSTART_OFF + (size_t)(NN + 256) * 4) // int[NN] histogram
#define ROFS_OFF   (RCNT_OFF + (size_t)NN * 4)         // int[NN] scatter cursors
#define WS_V6      (ROFS_OFF + (size_t)NN * 4)         // ~58.4 MB (< proven 61.6 MB)

#define NTILES (EE / 64)      // 12500 exact

// LDS pitches (bf16 elems)
#define PA 304   // v2 edge A pitch
#define PB 40    // B chunk pitch (32 + 8 pad; 80B stride = 2-way bank alias, free)
#define PN 272   // node A pitch (256 + 16 pad)
#define PH 136   // h/x pitch (128 + 8 pad; 272B rows, 16B-aligned)

// ---- dtype-detect ----
__global__ void detect_kernel(const unsigned short* __restrict__ xraw,
                              const unsigned int* __restrict__ eiraw,
                              int* __restrict__ flags)
{
    int cnt = 0;
    for (int i = 0; i < 64; ++i) {
        unsigned short u = xraw[2 * i];
        int ex = (u >> 7) & 0xFF;
        if (ex >= 100 && ex <= 140) cnt++;
    }
    flags[0] = (cnt < 32) ? 1 : 0;   // 1 => fp32
    int zc = 0;
    for (int i = 0; i < 32; ++i)
        if (eiraw[2 * i + 1] == 0u) zc++;
    flags[1] = (zc >= 16) ? 1 : 0;   // 1 => int64
}

__device__ inline int load_idx(const void* ei, int i64, size_t pos)
{
    return i64 ? (int)((const long long*)ei)[pos] : ((const int*)ei)[pos];
}

// silu via v_rcp_f32: avoids the exact-div sequence; error << bf16 rounding.
__device__ inline float fast_silu(float v)
{
    float e = __expf(-v);
    return v * __builtin_amdgcn_rcpf(1.0f + e);
}

template <typename FT>
__device__ inline void cp8(bf16_t* dst, const FT* src)
{
    if constexpr (std::is_same<FT, float>::value) {
#pragma unroll
        for (int i = 0; i < 8; i += 4) {
            float4 v = *(const float4*)(src + i);
            dst[i + 0] = (bf16_t)v.x; dst[i + 1] = (bf16_t)v.y;
            dst[i + 2] = (bf16_t)v.z; dst[i + 3] = (bf16_t)v.w;
        }
    } else {
        *(bf16x8*)dst = *(const bf16x8*)src;
    }
}

__device__ inline void pk_atomic_add_bf16(bf16_t* addr, float lo, float hi)
{
#if __has_builtin(__builtin_amdgcn_global_atomic_fadd_v2bf16)
    union { bf16_t b[2]; v2s s; } pk;
    pk.b[0] = (bf16_t)lo;
    pk.b[1] = (bf16_t)hi;
    (void)__builtin_amdgcn_global_atomic_fadd_v2bf16((v2s*)addr, pk.s);
#else
    unsigned int* w = (unsigned int*)addr;
    unsigned int old = __hip_atomic_load(w, __ATOMIC_RELAXED, __HIP_MEMORY_SCOPE_AGENT);
    while (true) {
        union { unsigned int u; bf16_t b[2]; } cur;
        cur.u = old;
        cur.b[0] = (bf16_t)((float)cur.b[0] + lo);
        cur.b[1] = (bf16_t)((float)cur.b[1] + hi);
        unsigned int prev = atomicCAS(w, old, cur.u);
        if (prev == old) break;
        old = prev;
    }
#endif
}

// ---- sort pass 1: 50K-bin histogram, fire-and-forget atomics (spread lines) ----
__global__ __launch_bounds__(256) void row_hist_kernel(
    const void* __restrict__ ei, int* __restrict__ rcnt, const int* __restrict__ flags)
{
    const int i64 = flags[1];
    size_t e = (size_t)blockIdx.x * 256 + threadIdx.x;
    int row = min(max(load_idx(ei, i64, e), 0), NN - 1);
    atomicAdd(&rcnt[row], 1);
}

// ---- sort pass 2: exclusive scan of 50K counts (single block, chunked) ----
__global__ __launch_bounds__(256) void row_scan_kernel(
    const int* __restrict__ rcnt, int* __restrict__ rstart)
{
    __shared__ int chunk[256];
    const int tid = threadIdx.x;
    const int C = (NN + 255) / 256;   // 196
    const int lo = tid * C;
    const int hi = min(lo + C, NN);
    int s = 0;
    for (int i = lo; i < hi; ++i) s += rcnt[i];
    chunk[tid] = s;
    __syncthreads();
    if (tid == 0) {
        int run = 0;
        for (int i = 0; i < 256; ++i) { int v = chunk[i]; chunk[i] = run; run += v; }
    }
    __syncthreads();
    int run = chunk[tid];
    for (int i = lo; i < hi; ++i) { rstart[i] = run; run += rcnt[i]; }
    if (tid == 255) rstart[NN] = run;   // == EE
}

// ---- sort pass 3: scatter, ONE 8B packed store per edge ----
__global__ __launch_bounds__(256) void row_scatter_kernel(
    const void* __restrict__ ei, const int* __restrict__ rstart,
    int* __restrict__ rofs, uint2* __restrict__ epk,
    const int* __restrict__ flags)
{
    const int i64 = flags[1];
    size_t e = (size_t)blockIdx.x * 256 + threadIdx.x;
    int row = min(max(load_idx(ei, i64, e), 0), NN - 1);
    int col = min(max(load_idx(ei, i64, (size_t)EE + e), 0), NN - 1);
    int pos = rstart[row] + atomicAdd(&rofs[row], 1);
    epk[pos] = make_uint2((unsigned)row | ((unsigned)col << 16), (unsigned)e);
}

// ---- prep: transpose weights -> bf16 ws; biases -> float ws ----
template <typename FT>
__global__ __launch_bounds__(256) void prep_kernel(
    const FT* __restrict__ eW1, const FT* __restrict__ eW2,
    const FT* __restrict__ nW1, const FT* __restrict__ nW2,
    const FT* __restrict__ b1, const FT* __restrict__ b2,
    const FT* __restrict__ nb1, const FT* __restrict__ nb2,
    bf16_t* __restrict__ W1t, bf16_t* __restrict__ W2t,
    bf16_t* __restrict__ nW1t, bf16_t* __restrict__ nW2t,
    float* __restrict__ biasF, const int* __restrict__ flags)
{
    constexpr int WANT = std::is_same<FT, float>::value ? 1 : 0;
    if (flags[0] != WANT) return;
    int idx = blockIdx.x * 256 + threadIdx.x;
    if (idx < 128 * 288) {
        int n = idx / 288;
        int k = idx - n * 288;
        W1t[idx] = (k < 272) ? (bf16_t)(float)eW1[k * 128 + n] : (bf16_t)0.0f;
    } else if (idx < 128 * 288 + 128 * 128) {
        int j = idx - 128 * 288;
        int n = j >> 7, k = j & 127;
        W2t[j] = (bf16_t)(float)eW2[k * 128 + n];
    } else if (idx < 128 * 288 + 128 * 128 + 128 * 256) {
        int j = idx - (128 * 288 + 128 * 128);
        int n = j >> 8, k = j & 255;
        nW1t[j] = (bf16_t)(float)nW1[k * 128 + n];
    } else if (idx < 102400) {
        int j = idx - (128 * 288 + 128 * 128 + 128 * 256);
        int n = j >> 7, k = j & 127;
        nW2t[j] = (bf16_t)(float)nW2[k * 128 + n];
    } else if (idx < 102912) {
        int j = idx - 102400;
        int which = j >> 7, c = j & 127;
        const FT* src = which == 0 ? b1 : which == 1 ? b2 : which == 2 ? nb1 : nb2;
        biasF[j] = (float)src[c];
    }
}

// ---- conv_x: x (FT) -> xb (bf16) ----
template <typename FT>
__global__ __launch_bounds__(256) void conv_x_kernel(
    const FT* __restrict__ x, bf16_t* __restrict__ xb,
    const int* __restrict__ flags)
{
    constexpr int WANT = std::is_same<FT, float>::value ? 1 : 0;
    if (flags[0] != WANT) return;
    size_t i = ((size_t)blockIdx.x * 256 + threadIdx.x) * 8;
    if (i >= (size_t)NN * DD) return;
    bf16x8 v;
    if constexpr (std::is_same<FT, float>::value) {
        float4 a = *(const float4*)(x + i);
        float4 b = *(const float4*)(x + i + 4);
        v[0] = (bf16_t)a.x; v[1] = (bf16_t)a.y; v[2] = (bf16_t)a.z; v[3] = (bf16_t)a.w;
        v[4] = (bf16_t)b.x; v[5] = (bf16_t)b.y; v[6] = (bf16_t)b.z; v[7] = (bf16_t)b.w;
    } else {
        v = *(const bf16x8*)(x + i);
    }
    *(bf16x8*)(xb + i) = v;
}

// ---- pq: P = xb @ eW1[0:128], Q = xb @ eW1[128:256] (both bf16 to ws) ----
__global__ __launch_bounds__(256) void pq_kernel(
    const bf16_t* __restrict__ xb, const bf16_t* __restrict__ W1t,
    bf16_t* __restrict__ P, bf16_t* __restrict__ Q)
{
    __shared__ bf16_t sX[64 * PH];
    __shared__ bf16_t sB[128 * PB];
    const int tid = threadIdx.x;
    const int n0 = blockIdx.x * 64;

    {
        const int m = tid >> 2;
        const int part = tid & 3;
        int n = n0 + m;
        if (n >= NN) n = NN - 1;
        const bf16x8* src = (const bf16x8*)(xb + (size_t)n * DD + part * 32);
        bf16x8* dst = (bf16x8*)&sX[m * PH + part * 32];
#pragma unroll
        for (int i = 0; i < 4; ++i) dst[i] = src[i];
    }

    const int lane = tid & 63;
    const int wv = tid >> 6;
    const int ml = lane & 15;
    const int q = lane >> 4;
    const int m0 = wv * 16;
    const floatx4 fzero = {0.f, 0.f, 0.f, 0.f};

    for (int pass = 0; pass < 2; ++pass) {
        floatx4 acc[8];
#pragma unroll
        for (int i = 0; i < 8; ++i) acc[i] = fzero;

        for (int kc = 0; kc < 4; ++kc) {
            __syncthreads();
            {
                const int n = tid >> 1;
                const int half = tid & 1;
                const bf16x8* src = (const bf16x8*)(W1t + n * 288 + pass * 128 + kc * 32 + half * 16);
                bf16x8* dst = (bf16x8*)&sB[n * PB + half * 16];
                dst[0] = src[0];
                dst[1] = src[1];
            }
            __syncthreads();
            const bf16x8 a = *(const bf16x8*)&sX[(m0 + ml) * PH + kc * 32 + q * 8];
#pragma unroll
            for (int nt = 0; nt < 8; ++nt) {
                const bf16x8 b = *(const bf16x8*)&sB[(nt * 16 + ml) * PB + q * 8];
                acc[nt] = __builtin_amdgcn_mfma_f32_16x16x32_bf16(a, b, acc[nt], 0, 0, 0);
            }
        }

        bf16_t* dst = pass ? Q : P;
#pragma unroll
        for (int r = 0; r < 4; ++r) {
            const int n = n0 + m0 + q * 4 + r;
#pragma unroll
            for (int nt = 0; nt < 8; ++nt) {
                float v = acc[nt][r];
                const float pv = __shfl_xor(v, 1, 64);
                if (((lane & 1) == 0) && n < NN) {
                    union { bf16_t b[2]; unsigned int u; } pk;
                    pk.b[0] = (bf16_t)v;
                    pk.b[1] = (bf16_t)pv;
                    *(unsigned int*)(dst + (size_t)n * DD + nt * 16 + ml) = pk.u;
                }
            }
        }
    }
}

// ======== edge v6: row-sorted edges + in-tile segment merge (8x fewer atomics) ====
// Edges sorted by destination row (packed uint2). Per wave (16 edges), lane owns
// one col-pair; a wave-uniform scan over sIdx sums same-row edges in f32 and
// emits ONE coalesced packed-bf16 atomic per (segment, col-pair).
__global__ __launch_bounds__(256) void edge_kernel_v6(
    const uint2* __restrict__ epk, const void* __restrict__ ea,
    const bf16_t* __restrict__ P, const bf16_t* __restrict__ Q,
    const bf16_t* __restrict__ W1t, const bf16_t* __restrict__ W2t,
    const float* __restrict__ biasF,
    bf16_t* __restrict__ agg, const int* __restrict__ flags)
{
    const int f32 = flags[0];

    __shared__ bf16_t sH[64 * PH];    // P+Q sum -> h -> m (all wave-private rows)
    __shared__ bf16_t sEA[64 * 32];   // ea tile, k 16..31 zero
    __shared__ bf16_t sB[128 * PB];   // B staging: W1t ea-chunk, then W2 chunks
    __shared__ int    sIdx[64];       // sorted dest row per edge

    const int tid = threadIdx.x;
    const int t = blockIdx.x;         // one 64-edge tile per block

    // ---- stage: sH = bf16(P[row]+Q[col]); sEA; sB = W1t ea-chunk ----
    {
        const int m = tid >> 2;
        const int part = tid & 3;
        const uint2 v = epk[(size_t)t * 64 + m];
        const int rn = (int)(v.x & 0xFFFFu);
        const int cn = (int)(v.x >> 16);
        if (part == 0) sIdx[m] = rn;
        const bf16x8* pr = (const bf16x8*)(P + (size_t)rn * DD + part * 32);
        const bf16x8* qc = (const bf16x8*)(Q + (size_t)cn * DD + part * 32);
#pragma unroll
        for (int i = 0; i < 4; ++i) {
            bf16x8 a = pr[i], b = qc[i], o;
#pragma unroll
            for (int j = 0; j < 8; ++j) o[j] = (bf16_t)((float)a[j] + (float)b[j]);
            *(bf16x8*)&sH[m * PH + part * 32 + i * 8] = o;
        }
        if (part < 2) {
            const int ep = (int)v.y;
            if (f32) cp8<float>(&sEA[m * 32 + part * 8], (const float*)ea + (size_t)ep * 16 + part * 8);
            else     cp8<bf16_t>(&sEA[m * 32 + part * 8], (const bf16_t*)ea + (size_t)ep * 16 + part * 8);
        } else {
            *(float4*)&sEA[m * 32 + part * 8] = make_float4(0.f, 0.f, 0.f, 0.f);
        }
        {
            const int n = tid >> 1;
            const int half = tid & 1;
            const bf16x8* src = (const bf16x8*)(W1t + n * 288 + 256 + half * 16);
            bf16x8* dst = (bf16x8*)&sB[n * PB + half * 16];
            dst[0] = src[0];
            dst[1] = src[1];
        }
    }
    __syncthreads();

    const int lane = tid & 63;
    const int wv = tid >> 6;
    const int ml = lane & 15;
    const int q = lane >> 4;
    const int m0 = wv * 16;
    const floatx4 fzero = {0.f, 0.f, 0.f, 0.f};

    // ---- ea contribution: one K=32 MFMA chunk ----
    floatx4 acc[8];
    {
        const bf16x8 a = *(const bf16x8*)&sEA[(m0 + ml) * 32 + q * 8];
#pragma unroll
        for (int nt = 0; nt < 8; ++nt) {
            const bf16x8 b = *(const bf16x8*)&sB[(nt * 16 + ml) * PB + q * 8];
            acc[nt] = __builtin_amdgcn_mfma_f32_16x16x32_bf16(a, b, fzero, 0, 0, 0);
        }
    }

    // ---- h = silu(acc + (P+Q) + b1), in place (wave-local rows) ----
#pragma unroll
    for (int nt = 0; nt < 8; ++nt) {
        const float bias = biasF[nt * 16 + ml];
#pragma unroll
        for (int r = 0; r < 4; ++r) {
            const int row = m0 + q * 4 + r;
            const int col = nt * 16 + ml;
            float v = acc[nt][r] + bias + (float)sH[row * PH + col];
            sH[row * PH + col] = (bf16_t)fast_silu(v);
        }
    }

    floatx4 acc2[8];
#pragma unroll
    for (int i = 0; i < 8; ++i) acc2[i] = fzero;

    // ---- layer 2: [64x128] @ [128x128], 4 K-chunks ----
    for (int kc = 0; kc < 4; ++kc) {
        __syncthreads();
        {
            const int n = tid >> 1;
            const int half = tid & 1;
            const bf16x8* src = (const bf16x8*)(W2t + n * 128 + kc * 32 + half * 16);
            bf16x8* dst = (bf16x8*)&sB[n * PB + half * 16];
            dst[0] = src[0];
            dst[1] = src[1];
        }
        __syncthreads();
        const bf16x8 a = *(const bf16x8*)&sH[(m0 + ml) * PH + kc * 32 + q * 8];
#pragma unroll
        for (int nt = 0; nt < 8; ++nt) {
            const bf16x8 b = *(const bf16x8*)&sB[(nt * 16 + ml) * PB + q * 8];
            acc2[nt] = __builtin_amdgcn_mfma_f32_16x16x32_bf16(a, b, acc2[nt], 0, 0, 0);
        }
    }

    // ---- m = silu(acc2 + b2) -> sH (wave-private rows; h dead now) ----
#pragma unroll
    for (int r = 0; r < 4; ++r) {
#pragma unroll
        for (int nt = 0; nt < 8; ++nt) {
            float v = fast_silu(acc2[nt][r] + biasF[128 + nt * 16 + ml]);
            const float pv = __shfl_xor(v, 1, 64);
            if ((ml & 1) == 0) {
                union { bf16_t b[2]; unsigned int u; } pk;
                pk.b[0] = (bf16_t)v;
                pk.b[1] = (bf16_t)pv;
                *(unsigned int*)&sH[(m0 + q * 4 + r) * PH + nt * 16 + ml] = pk.u;
            }
        }
    }

    // ---- wave-local segment reduce over sorted rows; one atomic per segment ----
    // lane owns col-pair `lane` (cols 2*lane, 2*lane+1); branch is wave-uniform.
    {
        float lo = 0.f, hi = 0.f;
        int curRow = sIdx[m0];
#pragma unroll
        for (int i = 0; i < 16; ++i) {
            const int r = sIdx[m0 + i];
            if (r != curRow) {
                pk_atomic_add_bf16(agg + (size_t)curRow * DD + lane * 2, lo, hi);
                lo = 0.f; hi = 0.f;
                curRow = r;
            }
            union { unsigned int u; bf16_t b[2]; } pk;
            pk.u = *(const unsigned int*)&sH[(m0 + i) * PH + lane * 2];
            lo += (float)pk.b[0];
            hi += (float)pk.b[1];
        }
        pk_atomic_add_bf16(agg + (size_t)curRow * DD + lane * 2, lo, hi);
    }
}

// ======== edge v3 (fallback: ws fits P/Q but not sort arrays) ========
__global__ __launch_bounds__(256) void edge_kernel_v3(
    const void* __restrict__ ei, const void* __restrict__ ea,
    const bf16_t* __restrict__ P, const bf16_t* __restrict__ Q,
    const bf16_t* __restrict__ W1t, const bf16_t* __restrict__ W2t,
    const float* __restrict__ biasF,
    bf16_t* __restrict__ agg, const int* __restrict__ flags)
{
    const int f32 = flags[0];
    const int i64 = flags[1];

    __shared__ bf16_t sH[64 * PH];
    __shared__ bf16_t sEA[64 * 32];
    __shared__ bf16_t sB[128 * PB];
    const int tid = threadIdx.x;
    const int e0 = blockIdx.x * 64;

    {
        const int m = tid >> 2;
        const int part = tid & 3;
        const int e = e0 + m;
        int rn = load_idx(ei, i64, e);
        int cn = load_idx(ei, i64, (size_t)EE + e);
        rn = min(max(rn, 0), NN - 1);
        cn = min(max(cn, 0), NN - 1);
        const bf16x8* pr = (const bf16x8*)(P + (size_t)rn * DD + part * 32);
        const bf16x8* qc = (const bf16x8*)(Q + (size_t)cn * DD + part * 32);
#pragma unroll
        for (int i = 0; i < 4; ++i) {
            bf16x8 a = pr[i], b = qc[i], o;
#pragma unroll
            for (int j = 0; j < 8; ++j) o[j] = (bf16_t)((float)a[j] + (float)b[j]);
            *(bf16x8*)&sH[m * PH + part * 32 + i * 8] = o;
        }
        if (part < 2) {
            if (f32) cp8<float>(&sEA[m * 32 + part * 8], (const float*)ea + (size_t)e * 16 + part * 8);
            else     cp8<bf16_t>(&sEA[m * 32 + part * 8], (const bf16_t*)ea + (size_t)e * 16 + part * 8);
        } else {
            *(float4*)&sEA[m * 32 + part * 8] = make_float4(0.f, 0.f, 0.f, 0.f);
        }
        {
            const int n = tid >> 1;
            const int half = tid & 1;
            const bf16x8* src = (const bf16x8*)(W1t + n * 288 + 256 + half * 16);
            bf16x8* dst = (bf16x8*)&sB[n * PB + half * 16];
            dst[0] = src[0];
            dst[1] = src[1];
        }
    }
    __syncthreads();

    const int lane = tid & 63;
    const int wv = tid >> 6;
    const int ml = lane & 15;
    const int q = lane >> 4;
    const int m0 = wv * 16;
    const floatx4 fzero = {0.f, 0.f, 0.f, 0.f};

    floatx4 acc[8];
#pragma unroll
    for (int i = 0; i < 8; ++i) acc[i] = fzero;
    {
        const bf16x8 a = *(const bf16x8*)&sEA[(m0 + ml) * 32 + q * 8];
#pragma unroll
        for (int nt = 0; nt < 8; ++nt) {
            const bf16x8 b = *(const bf16x8*)&sB[(nt * 16 + ml) * PB + q * 8];
            acc[nt] = __builtin_amdgcn_mfma_f32_16x16x32_bf16(a, b, acc[nt], 0, 0, 0);
        }
    }

#pragma unroll
    for (int nt = 0; nt < 8; ++nt) {
        const float bias = biasF[nt * 16 + ml];
#pragma unroll
        for (int r = 0; r < 4; ++r) {
            const int row = m0 + q * 4 + r;
            const int col = nt * 16 + ml;
            float v = acc[nt][r] + bias + (float)sH[row * PH + col];
            sH[row * PH + col] = (bf16_t)fast_silu(v);
        }
    }

    floatx4 acc2[8];
#pragma unroll
    for (int i = 0; i < 8; ++i) acc2[i] = fzero;

    for (int kc = 0; kc < 4; ++kc) {
        __syncthreads();
        {
            const int n = tid >> 1;
            const int half = tid & 1;
            const bf16x8* src = (const bf16x8*)(W2t + n * 128 + kc * 32 + half * 16);
            bf16x8* dst = (bf16x8*)&sB[n * PB + half * 16];
            dst[0] = src[0];
            dst[1] = src[1];
        }
        __syncthreads();
        const bf16x8 a = *(const bf16x8*)&sH[(m0 + ml) * PH + kc * 32 + q * 8];
#pragma unroll
        for (int nt = 0; nt < 8; ++nt) {
            const bf16x8 b = *(const bf16x8*)&sB[(nt * 16 + ml) * PB + q * 8];
            acc2[nt] = __builtin_amdgcn_mfma_f32_16x16x32_bf16(a, b, acc2[nt], 0, 0, 0);
        }
    }

#pragma unroll
    for (int r = 0; r < 4; ++r) {
        const int e = e0 + m0 + q * 4 + r;
        int rn = load_idx(ei, i64, e);
        rn = min(max(rn, 0), NN - 1);
#pragma unroll
        for (int nt = 0; nt < 8; ++nt) {
            float v = fast_silu(acc2[nt][r] + biasF[128 + nt * 16 + ml]);
            const float pv = __shfl_xor(v, 1, 64);
            if ((ml & 1) == 0)
                pk_atomic_add_bf16(agg + (size_t)rn * DD + nt * 16 + ml, v, pv);
        }
    }
}

// ======== edge v2 (fallback if ws too small for P/Q) ========
__global__ __launch_bounds__(256) void edge_kernel_v2(
    const bf16_t* __restrict__ xb, const void* __restrict__ ei,
    const void* __restrict__ ea,
    const bf16_t* __restrict__ W1t, const bf16_t* __restrict__ W2t,
    const float* __restrict__ biasF,
    bf16_t* __restrict__ agg, const int* __restrict__ flags)
{
    const int f32 = flags[0];
    const int i64 = flags[1];

    __shared__ bf16_t sA[64 * PA];
    __shared__ bf16_t sB[128 * PB];
    const int tid = threadIdx.x;
    const int e0 = blockIdx.x * 64;

    {
        const int m = tid >> 2;
        const int part = tid & 3;
        const int e = e0 + m;
        int rn = load_idx(ei, i64, e);
        int cn = load_idx(ei, i64, (size_t)EE + e);
        rn = min(max(rn, 0), NN - 1);
        cn = min(max(cn, 0), NN - 1);
        const bf16x8* xr = (const bf16x8*)(xb + (size_t)rn * DD + part * 32);
        const bf16x8* xc = (const bf16x8*)(xb + (size_t)cn * DD + part * 32);
        bf16x8* dR = (bf16x8*)&sA[m * PA + part * 32];
        bf16x8* dC = (bf16x8*)&sA[m * PA + 128 + part * 32];
#pragma unroll
        for (int i = 0; i < 4; ++i) dR[i] = xr[i];
#pragma unroll
        for (int i = 0; i < 4; ++i) dC[i] = xc[i];
        if (part < 2) {
            if (f32) cp8<float>(&sA[m * PA + 256 + part * 8], (const float*)ea + (size_t)e * 16 + part * 8);
            else     cp8<bf16_t>(&sA[m * PA + 256 + part * 8], (const bf16_t*)ea + (size_t)e * 16 + part * 8);
        } else {
            *(float4*)&sA[m * PA + 256 + part * 8] = make_float4(0.f, 0.f, 0.f, 0.f);
        }
    }

    const int lane = tid & 63;
    const int wv = tid >> 6;
    const int ml = lane & 15;
    const int q = lane >> 4;
    const int m0 = wv * 16;

    const floatx4 fzero = {0.f, 0.f, 0.f, 0.f};
    floatx4 acc[8];
#pragma unroll
    for (int i = 0; i < 8; ++i) acc[i] = fzero;

    for (int kc = 0; kc < 9; ++kc) {
        __syncthreads();
        {
            const int n = tid >> 1;
            const int half = tid & 1;
            const bf16x8* src = (const bf16x8*)(W1t + n * 288 + kc * 32 + half * 16);
            bf16x8* dst = (bf16x8*)&sB[n * PB + half * 16];
            dst[0] = src[0];
            dst[1] = src[1];
        }
        __syncthreads();
        const bf16x8 a = *(const bf16x8*)&sA[(m0 + ml) * PA + kc * 32 + q * 8];
#pragma unroll
        for (int nt = 0; nt < 8; ++nt) {
            const bf16x8 b = *(const bf16x8*)&sB[(nt * 16 + ml) * PB + q * 8];
            acc[nt] = __builtin_amdgcn_mfma_f32_16x16x32_bf16(a, b, acc[nt], 0, 0, 0);
        }
    }

#pragma unroll
    for (int nt = 0; nt < 8; ++nt) {
        const float bias = biasF[nt * 16 + ml];
#pragma unroll
        for (int r = 0; r < 4; ++r) {
            float v = acc[nt][r] + bias;
            sA[(m0 + q * 4 + r) * PA + nt * 16 + ml] = (bf16_t)fast_silu(v);
        }
    }
    __syncthreads();

    floatx4 acc2[8];
#pragma unroll
    for (int i = 0; i < 8; ++i) acc2[i] = fzero;

    for (int kc = 0; kc < 4; ++kc) {
        __syncthreads();
        {
            const int n = tid >> 1;
            const int half = tid & 1;
            const bf16x8* src = (const bf16x8*)(W2t + n * 128 + kc * 32 + half * 16);
            bf16x8* dst = (bf16x8*)&sB[n * PB + half * 16];
            dst[0] = src[0];
            dst[1] = src[1];
        }
        __syncthreads();
        const bf16x8 a = *(const bf16x8*)&sA[(m0 + ml) * PA + kc * 32 + q * 8];
#pragma unroll
        for (int nt = 0; nt < 8; ++nt) {
            const bf16x8 b = *(const bf16x8*)&sB[(nt * 16 + ml) * PB + q * 8];
            acc2[nt] = __builtin_amdgcn_mfma_f32_16x16x32_bf16(a, b, acc2[nt], 0, 0, 0);
        }
    }

    float bias2[8];
#pragma unroll
    for (int nt = 0; nt < 8; ++nt) bias2[nt] = biasF[128 + nt * 16 + ml];
#pragma unroll
    for (int r = 0; r < 4; ++r) {
        const int e = e0 + m0 + q * 4 + r;
        int rn = load_idx(ei, i64, e);
        rn = min(max(rn, 0), NN - 1);
#pragma unroll
        for (int nt = 0; nt < 8; ++nt) {
            float v = fast_silu(acc2[nt][r] + bias2[nt]);
            const float pv = __shfl_xor(v, 1, 64);
            if ((ml & 1) == 0)
                pk_atomic_add_bf16(agg + (size_t)rn * DD + nt * 16 + ml, v, pv);
        }
    }
}

// -------- node MLP: out = x + (silu([xb|agg] @ nW1 + nb1) @ nW2 + nb2) --------
template <typename FT>
__global__ __launch_bounds__(256) void node_kernel_v2(
    const FT* __restrict__ x, const bf16_t* __restrict__ xb,
    const bf16_t* __restrict__ agg,
    const bf16_t* __restrict__ nW1t, const bf16_t* __restrict__ nW2t,
    const float* __restrict__ biasF,
    FT* __restrict__ out, const int* __restrict__ flags)
{
    constexpr int WANT = std::is_same<FT, float>::value ? 1 : 0;
    if (flags[0] != WANT) return;

    __shared__ bf16_t sA[64 * PN];
    __shared__ bf16_t sB[128 * PB];
    const int tid = threadIdx.x;
    const int n0 = blockIdx.x * 64;

    {
        const int m = tid >> 2;
        const int p = tid & 3;
        int n = n0 + m;
        if (n >= NN) n = NN - 1;
        const bf16_t* srcbase = (p < 2) ? xb : agg;
        const int col = (p & 1) * 64;
        const bf16x8* src = (const bf16x8*)(srcbase + (size_t)n * DD + col);
        bf16x8* dst = (bf16x8*)&sA[m * PN + (p >> 1) * 128 + col];
#pragma unroll
        for (int i = 0; i < 8; ++i) dst[i] = src[i];
    }

    const int lane = tid & 63;
    const int wv = tid >> 6;
    const int ml = lane & 15;
    const int q = lane >> 4;
    const int m0 = wv * 16;

    const floatx4 fzero = {0.f, 0.f, 0.f, 0.f};
    floatx4 acc[8];
#pragma unroll
    for (int i = 0; i < 8; ++i) acc[i] = fzero;

    for (int kc = 0; kc < 8; ++kc) {
        __syncthreads();
        {
            const int n = tid >> 1;
            const int half = tid & 1;
            const bf16x8* src = (const bf16x8*)(nW1t + n * 256 + kc * 32 + half * 16);
            bf16x8* dst = (bf16x8*)&sB[n * PB + half * 16];
            dst[0] = src[0];
            dst[1] = src[1];
        }
        __syncthreads();
        const bf16x8 a = *(const bf16x8*)&sA[(m0 + ml) * PN + kc * 32 + q * 8];
#pragma unroll
        for (int nt = 0; nt < 8; ++nt) {
            const bf16x8 b = *(const bf16x8*)&sB[(nt * 16 + ml) * PB + q * 8];
            acc[nt] = __builtin_amdgcn_mfma_f32_16x16x32_bf16(a, b, acc[nt], 0, 0, 0);
        }
    }

#pragma unroll
    for (int nt = 0; nt < 8; ++nt) {
        const float bias = biasF[256 + nt * 16 + ml];
#pragma unroll
        for (int r = 0; r < 4; ++r) {
            float v = acc[nt][r] + bias;
            sA[(m0 + q * 4 + r) * PN + nt * 16 + ml] = (bf16_t)fast_silu(v);
        }
    }
    __syncthreads();

    floatx4 acc2[8];
#pragma unroll
    for (int i = 0; i < 8; ++i) acc2[i] = fzero;

    for (int kc = 0; kc < 4; ++kc) {
        __syncthreads();
        {
            const int n = tid >> 1;
            const int half = tid & 1;
            const bf16x8* src = (const bf16x8*)(nW2t + n * 128 + kc * 32 + half * 16);
            bf16x8* dst = (bf16x8*)&sB[n * PB + half * 16];
            dst[0] = src[0];
            dst[1] = src[1];
        }
        __syncthreads();
        const bf16x8 a = *(const bf16x8*)&sA[(m0 + ml) * PN + kc * 32 + q * 8];
#pragma unroll
        for (int nt = 0; nt < 8; ++nt) {
            const bf16x8 b = *(const bf16x8*)&sB[(nt * 16 + ml) * PB + q * 8];
            acc2[nt] = __builtin_amdgcn_mfma_f32_16x16x32_bf16(a, b, acc2[nt], 0, 0, 0);
        }
    }

#pragma unroll
    for (int r = 0; r < 4; ++r) {
        const int n = n0 + m0 + q * 4 + r;
        if (n < NN) {
#pragma unroll
            for (int nt = 0; nt < 8; ++nt) {
                const int col = nt * 16 + ml;
                float v = acc2[nt][r] + biasF[384 + col];
                float xv = (float)x[(size_t)n * DD + col];
                out[(size_t)n * DD + col] = (FT)(xv + v);
            }
        }
    }
}

extern "C" void kernel_launch(void* const* d_in, const int* in_sizes, int n_in,
                              void* d_out, int out_size, void* d_ws, size_t ws_size,
                              hipStream_t stream)
{
    const void* x   = d_in[0];
    const void* ei  = d_in[1];
    const void* ea  = d_in[2];
    const void* eW1 = d_in[3];
    const void* eb1 = d_in[4];
    const void* eW2 = d_in[5];
    const void* eb2 = d_in[6];
    const void* nW1 = d_in[7];
    const void* nb1 = d_in[8];
    const void* nW2 = d_in[9];
    const void* nb2 = d_in[10];

    char* ws = (char*)d_ws;
    int*    flags  = (int*)ws;
    bf16_t* W1t    = (bf16_t*)(ws + W1T_OFF);
    bf16_t* W2t    = (bf16_t*)(ws + W2T_OFF);
    bf16_t* nW1t   = (bf16_t*)(ws + NW1T_OFF);
    bf16_t* nW2t   = (bf16_t*)(ws + NW2T_OFF);
    float*  biasF  = (float*)(ws + BIASF_OFF);
    bf16_t* xb     = (bf16_t*)(ws + XB_OFF);
    bf16_t* agg    = (bf16_t*)(ws + AGG_OFF);
    bf16_t* P      = (bf16_t*)(ws + P_OFF);
    bf16_t* Q      = (bf16_t*)(ws + Q_OFF);
    uint2*  epk    = (uint2*)(ws + EPK_OFF);
    int*    rstart = (int*)(ws + RSTART_OFF);
    int*    rcnt   = (int*)(ws + RCNT_OFF);
    int*    rofs   = (int*)(ws + ROFS_OFF);

    detect_kernel<<<1, 1, 0, stream>>>((const unsigned short*)x,
                                       (const unsigned int*)ei, flags);

    prep_kernel<bf16_t><<<403, 256, 0, stream>>>(
        (const bf16_t*)eW1, (const bf16_t*)eW2, (const bf16_t*)nW1, (const bf16_t*)nW2,
        (const bf16_t*)eb1, (const bf16_t*)eb2, (const bf16_t*)nb1, (const bf16_t*)nb2,
        W1t, W2t, nW1t, nW2t, biasF, flags);
    prep_kernel<float><<<403, 256, 0, stream>>>(
        (const float*)eW1, (const float*)eW2, (const float*)nW1, (const float*)nW2,
        (const float*)eb1, (const float*)eb2, (const float*)nb1, (const float*)nb2,
        W1t, W2t, nW1t, nW2t, biasF, flags);

    (void)hipMemsetAsync(agg, 0, AGG_BYTES, stream);
    conv_x_kernel<bf16_t><<<3125, 256, 0, stream>>>((const bf16_t*)x, xb, flags);
    conv_x_kernel<float><<<3125, 256, 0, stream>>>((const float*)x, xb, flags);

    if (ws_size >= WS_V6) {
        (void)hipMemsetAsync(rcnt, 0, (size_t)2 * NN * 4, stream);   // rcnt + rofs contiguous
        row_hist_kernel<<<EE / 256, 256, 0, stream>>>(ei, rcnt, flags);
        row_scan_kernel<<<1, 256, 0, stream>>>(rcnt, rstart);
        row_scatter_kernel<<<EE / 256, 256, 0, stream>>>(ei, rstart, rofs, epk, flags);
        pq_kernel<<<(NN + 63) / 64, 256, 0, stream>>>(xb, W1t, P, Q);
        edge_kernel_v6<<<NTILES, 256, 0, stream>>>(epk, ea, P, Q,
                                                   W1t, W2t, biasF, agg, flags);
    } else if (ws_size >= WS_V3) {
        pq_kernel<<<(NN + 63) / 64, 256, 0, stream>>>(xb, W1t, P, Q);
        edge_kernel_v3<<<EE / 64, 256, 0, stream>>>(ei, ea, P, Q, W1t, W2t, biasF, agg, flags);
    } else {
        edge_kernel_v2<<<EE / 64, 256, 0, stream>>>(xb, ei, ea, W1t, W2t, biasF, agg, flags);
    }

    node_kernel_v2<bf16_t><<<(NN + 63) / 64, 256, 0, stream>>>(
        (const bf16_t*)x, xb, agg, nW1t, nW2t, biasF, (bf16_t*)d_out, flags);
    node_kernel_v2<float><<<(NN + 63) / 64, 256, 0, stream>>>(
        (const float*)x, xb, agg, nW1t, nW2t, biasF, (float*)d_out, flags);
}

// Round 7
// 504.091 us; speedup vs baseline: 5.6461x; 1.0160x over previous
//
#include <hip/hip_runtime.h>
#include <hip/hip_bf16.h>
#include <type_traits>

typedef __bf16 bf16_t;
typedef __bf16 bf16x8 __attribute__((ext_vector_type(8)));
typedef float floatx4 __attribute__((ext_vector_type(4)));
typedef short v2s __attribute__((ext_vector_type(2)));

#define NN 50000
#define EE 800000
#define DD 128

// ---- ws layout (bytes) ----
#define W1T_OFF   256                                  // [128][288] (K 272->288 zero-pad)
#define W2T_OFF   (W1T_OFF + (size_t)128 * 288 * 2)    // [128][128]
#define NW1T_OFF  (W2T_OFF + (size_t)128 * 128 * 2)    // [128][256]
#define NW2T_OFF  (NW1T_OFF + (size_t)128 * 256 * 2)   // [128][128]
#define BIASF_OFF (NW2T_OFF + (size_t)128 * 128 * 2)   // float[512]: b1|b2|nb1|nb2
#define XB_OFF    207360                               // bf16 x copy [NN][DD]
#define AGG_OFF   (XB_OFF + (size_t)NN * DD * 2)       // bf16 agg [NN][DD]
#define AGG_BYTES ((size_t)NN * DD * 2)
#define WS_V2     (AGG_OFF + AGG_BYTES)                // 25,807,360 (proven available)
#define P_OFF     WS_V2                                // bf16 P = x @ eW1[0:128]
#define Q_OFF     (P_OFF + (size_t)NN * DD * 2)        // bf16 Q = x @ eW1[128:256]
#define WS_V3     (Q_OFF + (size_t)NN * DD * 2)        // 51,407,360 (proven available)
// v6 sort: packed uint2 per edge = {row | col<<16, perm}
#define EPK_OFF    WS_V3                               // uint2[EE]
#define RSTART_OFF (EPK_OFF + (size_t)EE * 8)          // int[NN+1]
#define RCNT_OFF   (RSTART_OFF + (size_t)(NN + 256) * 4) // int[NN]
#define ROFS_OFF   (RCNT_OFF + (size_t)NN * 4)         // int[NN]
#define WS_V6      (ROFS_OFF + (size_t)NN * 4)         // ~58.4 MB (< proven 61.6 MB)

#define NTILES (EE / 64)      // 12500 exact
#define NB_CONV 3125          // conv/hist/zero blocks (3125*2048 = 6.4M elems exact)
#define NB_PREP 403           // weight-prep blocks
#define NB_K1   (NB_CONV + NB_PREP)

// LDS pitches (bf16 elems)
#define PA 304   // v2 edge A pitch
#define PB 48    // B chunk pitch (32 + 16 pad) -- PB=40 regressed bank conflicts (r6)
#define PN 272   // node A pitch (256 + 16 pad)
#define PH 136   // h/x pitch (128 + 8 pad)

__device__ inline int load_idx(const void* ei, int i64, size_t pos)
{
    return i64 ? (int)((const long long*)ei)[pos] : ((const int*)ei)[pos];
}

// silu via v_rcp_f32: avoids the exact-div sequence; error << bf16 rounding.
__device__ inline float fast_silu(float v)
{
    float e = __expf(-v);
    return v * __builtin_amdgcn_rcpf(1.0f + e);
}

__device__ inline float ldf(const void* p, int f32, size_t i)
{
    return f32 ? ((const float*)p)[i] : (float)((const bf16_t*)p)[i];
}

template <typename FT>
__device__ inline void cp8(bf16_t* dst, const FT* src)
{
    if constexpr (std::is_same<FT, float>::value) {
#pragma unroll
        for (int i = 0; i < 8; i += 4) {
            float4 v = *(const float4*)(src + i);
            dst[i + 0] = (bf16_t)v.x; dst[i + 1] = (bf16_t)v.y;
            dst[i + 2] = (bf16_t)v.z; dst[i + 3] = (bf16_t)v.w;
        }
    } else {
        *(bf16x8*)dst = *(const bf16x8*)src;
    }
}

__device__ inline void pk_atomic_add_bf16(bf16_t* addr, float lo, float hi)
{
#if __has_builtin(__builtin_amdgcn_global_atomic_fadd_v2bf16)
    union { bf16_t b[2]; v2s s; } pk;
    pk.b[0] = (bf16_t)lo;
    pk.b[1] = (bf16_t)hi;
    (void)__builtin_amdgcn_global_atomic_fadd_v2bf16((v2s*)addr, pk.s);
#else
    unsigned int* w = (unsigned int*)addr;
    unsigned int old = __hip_atomic_load(w, __ATOMIC_RELAXED, __HIP_MEMORY_SCOPE_AGENT);
    while (true) {
        union { unsigned int u; bf16_t b[2]; } cur;
        cur.u = old;
        cur.b[0] = (bf16_t)((float)cur.b[0] + lo);
        cur.b[1] = (bf16_t)((float)cur.b[1] + hi);
        unsigned int prev = atomicCAS(w, old, cur.u);
        if (prev == old) break;
        old = prev;
    }
#endif
}

// ======== K1: fused detect + conv_x + agg-zero + row-hist + weight-prep ========
// blocks [0, NB_CONV): conv_x 2048-elem slice, zero agg slice, hist 256 edges
// blocks [NB_CONV, NB_K1): weight/bias transpose (same indexing as old prep)
// block 0 tid 0 publishes flags to ws for later kernels.
__global__ __launch_bounds__(256) void fused_prep_kernel(
    const void* __restrict__ x, const void* __restrict__ ei,
    const void* __restrict__ eW1, const void* __restrict__ eW2,
    const void* __restrict__ nW1, const void* __restrict__ nW2,
    const void* __restrict__ b1, const void* __restrict__ b2,
    const void* __restrict__ nb1, const void* __restrict__ nb2,
    bf16_t* __restrict__ W1t, bf16_t* __restrict__ W2t,
    bf16_t* __restrict__ nW1t, bf16_t* __restrict__ nW2t,
    float* __restrict__ biasF, bf16_t* __restrict__ xb,
    bf16_t* __restrict__ agg, int* __restrict__ rcnt,
    int* __restrict__ flags, int do_sort)
{
    __shared__ int sf[2];
    const int tid = threadIdx.x;
    const int b = blockIdx.x;

    if (tid == 0) {
        const unsigned short* xraw = (const unsigned short*)x;
        const unsigned int* eiraw = (const unsigned int*)ei;
        int cnt = 0;
#pragma unroll
        for (int i = 0; i < 64; ++i) {
            unsigned short u = xraw[2 * i];
            int ex = (u >> 7) & 0xFF;
            if (ex >= 100 && ex <= 140) cnt++;
        }
        int zc = 0;
#pragma unroll
        for (int i = 0; i < 32; ++i)
            if (eiraw[2 * i + 1] == 0u) zc++;
        sf[0] = (cnt < 32) ? 1 : 0;   // 1 => fp32
        sf[1] = (zc >= 16) ? 1 : 0;   // 1 => int64
        if (b == 0) { flags[0] = sf[0]; flags[1] = sf[1]; }
    }
    __syncthreads();
    const int f32 = sf[0];
    const int i64 = sf[1];

    if (b < NB_CONV) {
        // conv_x + agg zero (exact coverage: 3125*2048 = 6.4M)
        size_t i = ((size_t)b * 256 + tid) * 8;
        bf16x8 v;
        if (f32) {
            float4 a = *(const float4*)((const float*)x + i);
            float4 c = *(const float4*)((const float*)x + i + 4);
            v[0] = (bf16_t)a.x; v[1] = (bf16_t)a.y; v[2] = (bf16_t)a.z; v[3] = (bf16_t)a.w;
            v[4] = (bf16_t)c.x; v[5] = (bf16_t)c.y; v[6] = (bf16_t)c.z; v[7] = (bf16_t)c.w;
        } else {
            v = *(const bf16x8*)((const bf16_t*)x + i);
        }
        *(bf16x8*)(xb + i) = v;
        bf16x8 z;
#pragma unroll
        for (int j = 0; j < 8; ++j) z[j] = (bf16_t)0.0f;
        *(bf16x8*)(agg + i) = z;
        if (do_sort) {
            size_t e = (size_t)b * 256 + tid;   // exact: 3125*256 = 800000
            int row = min(max(load_idx(ei, i64, e), 0), NN - 1);
            atomicAdd(&rcnt[row], 1);
        }
    } else {
        int idx = (b - NB_CONV) * 256 + tid;
        if (idx < 128 * 288) {
            int n = idx / 288;
            int k = idx - n * 288;
            W1t[idx] = (k < 272) ? (bf16_t)ldf(eW1, f32, (size_t)k * 128 + n) : (bf16_t)0.0f;
        } else if (idx < 128 * 288 + 128 * 128) {
            int j = idx - 128 * 288;
            int n = j >> 7, k = j & 127;
            W2t[j] = (bf16_t)ldf(eW2, f32, (size_t)k * 128 + n);
        } else if (idx < 128 * 288 + 128 * 128 + 128 * 256) {
            int j = idx - (128 * 288 + 128 * 128);
            int n = j >> 8, k = j & 255;
            nW1t[j] = (bf16_t)ldf(nW1, f32, (size_t)k * 128 + n);
        } else if (idx < 102400) {
            int j = idx - (128 * 288 + 128 * 128 + 128 * 256);
            int n = j >> 7, k = j & 127;
            nW2t[j] = (bf16_t)ldf(nW2, f32, (size_t)k * 128 + n);
        } else if (idx < 102912) {
            int j = idx - 102400;
            int which = j >> 7, c = j & 127;
            const void* src = which == 0 ? b1 : which == 1 ? b2 : which == 2 ? nb1 : nb2;
            biasF[j] = ldf(src, f32, c);
        }
    }
}

// ---- sort scatter: one returning atomic + one 8B packed store per edge ----
__global__ __launch_bounds__(256) void row_scatter_kernel(
    const void* __restrict__ ei, const int* __restrict__ rstart,
    int* __restrict__ rofs, uint2* __restrict__ epk,
    const int* __restrict__ flags)
{
    const int i64 = flags[1];
    size_t e = (size_t)blockIdx.x * 256 + threadIdx.x;
    int row = min(max(load_idx(ei, i64, e), 0), NN - 1);
    int col = min(max(load_idx(ei, i64, (size_t)EE + e), 0), NN - 1);
    int pos = rstart[row] + atomicAdd(&rofs[row], 1);
    epk[pos] = make_uint2((unsigned)row | ((unsigned)col << 16), (unsigned)e);
}

// ---- pq: P = xb @ eW1[0:128], Q = xb @ eW1[128:256]; last block runs the scan ----
__global__ __launch_bounds__(256) void pq_kernel(
    const bf16_t* __restrict__ xb, const bf16_t* __restrict__ W1t,
    bf16_t* __restrict__ P, bf16_t* __restrict__ Q,
    const int* __restrict__ rcnt, int* __restrict__ rstart, int do_scan)
{
    __shared__ bf16_t sX[64 * PH];
    __shared__ bf16_t sB[128 * PB];
    __shared__ int chunk[256];
    const int tid = threadIdx.x;

    if (do_scan && blockIdx.x == gridDim.x - 1) {
        // 50K exclusive scan, overlapped with pq blocks
        const int C = (NN + 255) / 256;   // 196
        const int lo = tid * C;
        const int hi = min(lo + C, NN);
        int s = 0;
        for (int i = lo; i < hi; ++i) s += rcnt[i];
        chunk[tid] = s;
        __syncthreads();
        if (tid == 0) {
            int run = 0;
            for (int i = 0; i < 256; ++i) { int v = chunk[i]; chunk[i] = run; run += v; }
        }
        __syncthreads();
        int run = chunk[tid];
        for (int i = lo; i < hi; ++i) { rstart[i] = run; run += rcnt[i]; }
        if (tid == 255) rstart[NN] = run;   // == EE
        return;
    }

    const int n0 = blockIdx.x * 64;
    {
        const int m = tid >> 2;
        const int part = tid & 3;
        int n = n0 + m;
        if (n >= NN) n = NN - 1;
        const bf16x8* src = (const bf16x8*)(xb + (size_t)n * DD + part * 32);
        bf16x8* dst = (bf16x8*)&sX[m * PH + part * 32];
#pragma unroll
        for (int i = 0; i < 4; ++i) dst[i] = src[i];
    }

    const int lane = tid & 63;
    const int wv = tid >> 6;
    const int ml = lane & 15;
    const int q = lane >> 4;
    const int m0 = wv * 16;
    const floatx4 fzero = {0.f, 0.f, 0.f, 0.f};

    for (int pass = 0; pass < 2; ++pass) {
        floatx4 acc[8];
#pragma unroll
        for (int i = 0; i < 8; ++i) acc[i] = fzero;

        for (int kc = 0; kc < 4; ++kc) {
            __syncthreads();
            {
                const int n = tid >> 1;
                const int half = tid & 1;
                const bf16x8* src = (const bf16x8*)(W1t + n * 288 + pass * 128 + kc * 32 + half * 16);
                bf16x8* dst = (bf16x8*)&sB[n * PB + half * 16];
                dst[0] = src[0];
                dst[1] = src[1];
            }
            __syncthreads();
            const bf16x8 a = *(const bf16x8*)&sX[(m0 + ml) * PH + kc * 32 + q * 8];
#pragma unroll
            for (int nt = 0; nt < 8; ++nt) {
                const bf16x8 b = *(const bf16x8*)&sB[(nt * 16 + ml) * PB + q * 8];
                acc[nt] = __builtin_amdgcn_mfma_f32_16x16x32_bf16(a, b, acc[nt], 0, 0, 0);
            }
        }

        bf16_t* dst = pass ? Q : P;
#pragma unroll
        for (int r = 0; r < 4; ++r) {
            const int n = n0 + m0 + q * 4 + r;
#pragma unroll
            for (int nt = 0; nt < 8; ++nt) {
                float v = acc[nt][r];
                const float pv = __shfl_xor(v, 1, 64);
                if (((lane & 1) == 0) && n < NN) {
                    union { bf16_t b[2]; unsigned int u; } pk;
                    pk.b[0] = (bf16_t)v;
                    pk.b[1] = (bf16_t)pv;
                    *(unsigned int*)(dst + (size_t)n * DD + nt * 16 + ml) = pk.u;
                }
            }
        }
    }
}

// ======== edge v6: row-sorted edges + in-tile segment merge (proven, r5/r6) ========
__global__ __launch_bounds__(256) void edge_kernel_v6(
    const uint2* __restrict__ epk, const void* __restrict__ ea,
    const bf16_t* __restrict__ P, const bf16_t* __restrict__ Q,
    const bf16_t* __restrict__ W1t, const bf16_t* __restrict__ W2t,
    const float* __restrict__ biasF,
    bf16_t* __restrict__ agg, const int* __restrict__ flags)
{
    const int f32 = flags[0];

    __shared__ bf16_t sH[64 * PH];    // P+Q sum -> h -> m (all wave-private rows)
    __shared__ bf16_t sEA[64 * 32];   // ea tile, k 16..31 zero
    __shared__ bf16_t sB[128 * PB];   // B staging: W1t ea-chunk, then W2 chunks
    __shared__ int    sIdx[64];       // sorted dest row per edge

    const int tid = threadIdx.x;
    const int t = blockIdx.x;         // one 64-edge tile per block

    {
        const int m = tid >> 2;
        const int part = tid & 3;
        const uint2 v = epk[(size_t)t * 64 + m];
        const int rn = (int)(v.x & 0xFFFFu);
        const int cn = (int)(v.x >> 16);
        if (part == 0) sIdx[m] = rn;
        const bf16x8* pr = (const bf16x8*)(P + (size_t)rn * DD + part * 32);
        const bf16x8* qc = (const bf16x8*)(Q + (size_t)cn * DD + part * 32);
#pragma unroll
        for (int i = 0; i < 4; ++i) {
            bf16x8 a = pr[i], b = qc[i], o;
#pragma unroll
            for (int j = 0; j < 8; ++j) o[j] = (bf16_t)((float)a[j] + (float)b[j]);
            *(bf16x8*)&sH[m * PH + part * 32 + i * 8] = o;
        }
        if (part < 2) {
            const int ep = (int)v.y;
            if (f32) cp8<float>(&sEA[m * 32 + part * 8], (const float*)ea + (size_t)ep * 16 + part * 8);
            else     cp8<bf16_t>(&sEA[m * 32 + part * 8], (const bf16_t*)ea + (size_t)ep * 16 + part * 8);
        } else {
            *(float4*)&sEA[m * 32 + part * 8] = make_float4(0.f, 0.f, 0.f, 0.f);
        }
        {
            const int n = tid >> 1;
            const int half = tid & 1;
            const bf16x8* src = (const bf16x8*)(W1t + n * 288 + 256 + half * 16);
            bf16x8* dst = (bf16x8*)&sB[n * PB + half * 16];
            dst[0] = src[0];
            dst[1] = src[1];
        }
    }
    __syncthreads();

    const int lane = tid & 63;
    const int wv = tid >> 6;
    const int ml = lane & 15;
    const int q = lane >> 4;
    const int m0 = wv * 16;
    const floatx4 fzero = {0.f, 0.f, 0.f, 0.f};

    floatx4 acc[8];
    {
        const bf16x8 a = *(const bf16x8*)&sEA[(m0 + ml) * 32 + q * 8];
#pragma unroll
        for (int nt = 0; nt < 8; ++nt) {
            const bf16x8 b = *(const bf16x8*)&sB[(nt * 16 + ml) * PB + q * 8];
            acc[nt] = __builtin_amdgcn_mfma_f32_16x16x32_bf16(a, b, fzero, 0, 0, 0);
        }
    }

#pragma unroll
    for (int nt = 0; nt < 8; ++nt) {
        const float bias = biasF[nt * 16 + ml];
#pragma unroll
        for (int r = 0; r < 4; ++r) {
            const int row = m0 + q * 4 + r;
            const int col = nt * 16 + ml;
            float v = acc[nt][r] + bias + (float)sH[row * PH + col];
            sH[row * PH + col] = (bf16_t)fast_silu(v);
        }
    }

    floatx4 acc2[8];
#pragma unroll
    for (int i = 0; i < 8; ++i) acc2[i] = fzero;

    for (int kc = 0; kc < 4; ++kc) {
        __syncthreads();
        {
            const int n = tid >> 1;
            const int half = tid & 1;
            const bf16x8* src = (const bf16x8*)(W2t + n * 128 + kc * 32 + half * 16);
            bf16x8* dst = (bf16x8*)&sB[n * PB + half * 16];
            dst[0] = src[0];
            dst[1] = src[1];
        }
        __syncthreads();
        const bf16x8 a = *(const bf16x8*)&sH[(m0 + ml) * PH + kc * 32 + q * 8];
#pragma unroll
        for (int nt = 0; nt < 8; ++nt) {
            const bf16x8 b = *(const bf16x8*)&sB[(nt * 16 + ml) * PB + q * 8];
            acc2[nt] = __builtin_amdgcn_mfma_f32_16x16x32_bf16(a, b, acc2[nt], 0, 0, 0);
        }
    }

#pragma unroll
    for (int r = 0; r < 4; ++r) {
#pragma unroll
        for (int nt = 0; nt < 8; ++nt) {
            float v = fast_silu(acc2[nt][r] + biasF[128 + nt * 16 + ml]);
            const float pv = __shfl_xor(v, 1, 64);
            if ((ml & 1) == 0) {
                union { bf16_t b[2]; unsigned int u; } pk;
                pk.b[0] = (bf16_t)v;
                pk.b[1] = (bf16_t)pv;
                *(unsigned int*)&sH[(m0 + q * 4 + r) * PH + nt * 16 + ml] = pk.u;
            }
        }
    }

    {
        float lo = 0.f, hi = 0.f;
        int curRow = sIdx[m0];
#pragma unroll
        for (int i = 0; i < 16; ++i) {
            const int r = sIdx[m0 + i];
            if (r != curRow) {
                pk_atomic_add_bf16(agg + (size_t)curRow * DD + lane * 2, lo, hi);
                lo = 0.f; hi = 0.f;
                curRow = r;
            }
            union { unsigned int u; bf16_t b[2]; } pk;
            pk.u = *(const unsigned int*)&sH[(m0 + i) * PH + lane * 2];
            lo += (float)pk.b[0];
            hi += (float)pk.b[1];
        }
        pk_atomic_add_bf16(agg + (size_t)curRow * DD + lane * 2, lo, hi);
    }
}

// ======== edge v3 (fallback: ws fits P/Q but not sort arrays) ========
__global__ __launch_bounds__(256) void edge_kernel_v3(
    const void* __restrict__ ei, const void* __restrict__ ea,
    const bf16_t* __restrict__ P, const bf16_t* __restrict__ Q,
    const bf16_t* __restrict__ W1t, const bf16_t* __restrict__ W2t,
    const float* __restrict__ biasF,
    bf16_t* __restrict__ agg, const int* __restrict__ flags)
{
    const int f32 = flags[0];
    const int i64 = flags[1];

    __shared__ bf16_t sH[64 * PH];
    __shared__ bf16_t sEA[64 * 32];
    __shared__ bf16_t sB[128 * PB];
    const int tid = threadIdx.x;
    const int e0 = blockIdx.x * 64;

    {
        const int m = tid >> 2;
        const int part = tid & 3;
        const int e = e0 + m;
        int rn = load_idx(ei, i64, e);
        int cn = load_idx(ei, i64, (size_t)EE + e);
        rn = min(max(rn, 0), NN - 1);
        cn = min(max(cn, 0), NN - 1);
        const bf16x8* pr = (const bf16x8*)(P + (size_t)rn * DD + part * 32);
        const bf16x8* qc = (const bf16x8*)(Q + (size_t)cn * DD + part * 32);
#pragma unroll
        for (int i = 0; i < 4; ++i) {
            bf16x8 a = pr[i], b = qc[i], o;
#pragma unroll
            for (int j = 0; j < 8; ++j) o[j] = (bf16_t)((float)a[j] + (float)b[j]);
            *(bf16x8*)&sH[m * PH + part * 32 + i * 8] = o;
        }
        if (part < 2) {
            if (f32) cp8<float>(&sEA[m * 32 + part * 8], (const float*)ea + (size_t)e * 16 + part * 8);
            else     cp8<bf16_t>(&sEA[m * 32 + part * 8], (const bf16_t*)ea + (size_t)e * 16 + part * 8);
        } else {
            *(float4*)&sEA[m * 32 + part * 8] = make_float4(0.f, 0.f, 0.f, 0.f);
        }
        {
            const int n = tid >> 1;
            const int half = tid & 1;
            const bf16x8* src = (const bf16x8*)(W1t + n * 288 + 256 + half * 16);
            bf16x8* dst = (bf16x8*)&sB[n * PB + half * 16];
            dst[0] = src[0];
            dst[1] = src[1];
        }
    }
    __syncthreads();

    const int lane = tid & 63;
    const int wv = tid >> 6;
    const int ml = lane & 15;
    const int q = lane >> 4;
    const int m0 = wv * 16;
    const floatx4 fzero = {0.f, 0.f, 0.f, 0.f};

    floatx4 acc[8];
#pragma unroll
    for (int i = 0; i < 8; ++i) acc[i] = fzero;
    {
        const bf16x8 a = *(const bf16x8*)&sEA[(m0 + ml) * 32 + q * 8];
#pragma unroll
        for (int nt = 0; nt < 8; ++nt) {
            const bf16x8 b = *(const bf16x8*)&sB[(nt * 16 + ml) * PB + q * 8];
            acc[nt] = __builtin_amdgcn_mfma_f32_16x16x32_bf16(a, b, acc[nt], 0, 0, 0);
        }
    }

#pragma unroll
    for (int nt = 0; nt < 8; ++nt) {
        const float bias = biasF[nt * 16 + ml];
#pragma unroll
        for (int r = 0; r < 4; ++r) {
            const int row = m0 + q * 4 + r;
            const int col = nt * 16 + ml;
            float v = acc[nt][r] + bias + (float)sH[row * PH + col];
            sH[row * PH + col] = (bf16_t)fast_silu(v);
        }
    }

    floatx4 acc2[8];
#pragma unroll
    for (int i = 0; i < 8; ++i) acc2[i] = fzero;

    for (int kc = 0; kc < 4; ++kc) {
        __syncthreads();
        {
            const int n = tid >> 1;
            const int half = tid & 1;
            const bf16x8* src = (const bf16x8*)(W2t + n * 128 + kc * 32 + half * 16);
            bf16x8* dst = (bf16x8*)&sB[n * PB + half * 16];
            dst[0] = src[0];
            dst[1] = src[1];
        }
        __syncthreads();
        const bf16x8 a = *(const bf16x8*)&sH[(m0 + ml) * PH + kc * 32 + q * 8];
#pragma unroll
        for (int nt = 0; nt < 8; ++nt) {
            const bf16x8 b = *(const bf16x8*)&sB[(nt * 16 + ml) * PB + q * 8];
            acc2[nt] = __builtin_amdgcn_mfma_f32_16x16x32_bf16(a, b, acc2[nt], 0, 0, 0);
        }
    }

#pragma unroll
    for (int r = 0; r < 4; ++r) {
        const int e = e0 + m0 + q * 4 + r;
        int rn = load_idx(ei, i64, e);
        rn = min(max(rn, 0), NN - 1);
#pragma unroll
        for (int nt = 0; nt < 8; ++nt) {
            float v = fast_silu(acc2[nt][r] + biasF[128 + nt * 16 + ml]);
            const float pv = __shfl_xor(v, 1, 64);
            if ((ml & 1) == 0)
                pk_atomic_add_bf16(agg + (size_t)rn * DD + nt * 16 + ml, v, pv);
        }
    }
}

// ======== edge v2 (fallback if ws too small for P/Q) ========
__global__ __launch_bounds__(256) void edge_kernel_v2(
    const bf16_t* __restrict__ xb, const void* __restrict__ ei,
    const void* __restrict__ ea,
    const bf16_t* __restrict__ W1t, const bf16_t* __restrict__ W2t,
    const float* __restrict__ biasF,
    bf16_t* __restrict__ agg, const int* __restrict__ flags)
{
    const int f32 = flags[0];
    const int i64 = flags[1];

    __shared__ bf16_t sA[64 * PA];
    __shared__ bf16_t sB[128 * PB];
    const int tid = threadIdx.x;
    const int e0 = blockIdx.x * 64;

    {
        const int m = tid >> 2;
        const int part = tid & 3;
        const int e = e0 + m;
        int rn = load_idx(ei, i64, e);
        int cn = load_idx(ei, i64, (size_t)EE + e);
        rn = min(max(rn, 0), NN - 1);
        cn = min(max(cn, 0), NN - 1);
        const bf16x8* xr = (const bf16x8*)(xb + (size_t)rn * DD + part * 32);
        const bf16x8* xc = (const bf16x8*)(xb + (size_t)cn * DD + part * 32);
        bf16x8* dR = (bf16x8*)&sA[m * PA + part * 32];
        bf16x8* dC = (bf16x8*)&sA[m * PA + 128 + part * 32];
#pragma unroll
        for (int i = 0; i < 4; ++i) dR[i] = xr[i];
#pragma unroll
        for (int i = 0; i < 4; ++i) dC[i] = xc[i];
        if (part < 2) {
            if (f32) cp8<float>(&sA[m * PA + 256 + part * 8], (const float*)ea + (size_t)e * 16 + part * 8);
            else     cp8<bf16_t>(&sA[m * PA + 256 + part * 8], (const bf16_t*)ea + (size_t)e * 16 + part * 8);
        } else {
            *(float4*)&sA[m * PA + 256 + part * 8] = make_float4(0.f, 0.f, 0.f, 0.f);
        }
    }

    const int lane = tid & 63;
    const int wv = tid >> 6;
    const int ml = lane & 15;
    const int q = lane >> 4;
    const int m0 = wv * 16;

    const floatx4 fzero = {0.f, 0.f, 0.f, 0.f};
    floatx4 acc[8];
#pragma unroll
    for (int i = 0; i < 8; ++i) acc[i] = fzero;

    for (int kc = 0; kc < 9; ++kc) {
        __syncthreads();
        {
            const int n = tid >> 1;
            const int half = tid & 1;
            const bf16x8* src = (const bf16x8*)(W1t + n * 288 + kc * 32 + half * 16);
            bf16x8* dst = (bf16x8*)&sB[n * PB + half * 16];
            dst[0] = src[0];
            dst[1] = src[1];
        }
        __syncthreads();
        const bf16x8 a = *(const bf16x8*)&sA[(m0 + ml) * PA + kc * 32 + q * 8];
#pragma unroll
        for (int nt = 0; nt < 8; ++nt) {
            const bf16x8 b = *(const bf16x8*)&sB[(nt * 16 + ml) * PB + q * 8];
            acc[nt] = __builtin_amdgcn_mfma_f32_16x16x32_bf16(a, b, acc[nt], 0, 0, 0);
        }
    }

#pragma unroll
    for (int nt = 0; nt < 8; ++nt) {
        const float bias = biasF[nt * 16 + ml];
#pragma unroll
        for (int r = 0; r < 4; ++r) {
            float v = acc[nt][r] + bias;
            sA[(m0 + q * 4 + r) * PA + nt * 16 + ml] = (bf16_t)fast_silu(v);
        }
    }
    __syncthreads();

    floatx4 acc2[8];
#pragma unroll
    for (int i = 0; i < 8; ++i) acc2[i] = fzero;

    for (int kc = 0; kc < 4; ++kc) {
        __syncthreads();
        {
            const int n = tid >> 1;
            const int half = tid & 1;
            const bf16x8* src = (const bf16x8*)(W2t + n * 128 + kc * 32 + half * 16);
            bf16x8* dst = (bf16x8*)&sB[n * PB + half * 16];
            dst[0] = src[0];
            dst[1] = src[1];
        }
        __syncthreads();
        const bf16x8 a = *(const bf16x8*)&sA[(m0 + ml) * PA + kc * 32 + q * 8];
#pragma unroll
        for (int nt = 0; nt < 8; ++nt) {
            const bf16x8 b = *(const bf16x8*)&sB[(nt * 16 + ml) * PB + q * 8];
            acc2[nt] = __builtin_amdgcn_mfma_f32_16x16x32_bf16(a, b, acc2[nt], 0, 0, 0);
        }
    }

    float bias2[8];
#pragma unroll
    for (int nt = 0; nt < 8; ++nt) bias2[nt] = biasF[128 + nt * 16 + ml];
#pragma unroll
    for (int r = 0; r < 4; ++r) {
        const int e = e0 + m0 + q * 4 + r;
        int rn = load_idx(ei, i64, e);
        rn = min(max(rn, 0), NN - 1);
#pragma unroll
        for (int nt = 0; nt < 8; ++nt) {
            float v = fast_silu(acc2[nt][r] + bias2[nt]);
            const float pv = __shfl_xor(v, 1, 64);
            if ((ml & 1) == 0)
                pk_atomic_add_bf16(agg + (size_t)rn * DD + nt * 16 + ml, v, pv);
        }
    }
}

// -------- node MLP (runtime dtype): out = x + (silu([xb|agg]@nW1+nb1)@nW2+nb2) ----
__global__ __launch_bounds__(256) void node_kernel_v3(
    const void* __restrict__ x, const bf16_t* __restrict__ xb,
    const bf16_t* __restrict__ agg,
    const bf16_t* __restrict__ nW1t, const bf16_t* __restrict__ nW2t,
    const float* __restrict__ biasF,
    void* __restrict__ out, const int* __restrict__ flags)
{
    const int f32 = flags[0];

    __shared__ bf16_t sA[64 * PN];
    __shared__ bf16_t sB[128 * PB];
    const int tid = threadIdx.x;
    const int n0 = blockIdx.x * 64;

    {
        const int m = tid >> 2;
        const int p = tid & 3;
        int n = n0 + m;
        if (n >= NN) n = NN - 1;
        const bf16_t* srcbase = (p < 2) ? xb : agg;
        const int col = (p & 1) * 64;
        const bf16x8* src = (const bf16x8*)(srcbase + (size_t)n * DD + col);
        bf16x8* dst = (bf16x8*)&sA[m * PN + (p >> 1) * 128 + col];
#pragma unroll
        for (int i = 0; i < 8; ++i) dst[i] = src[i];
    }

    const int lane = tid & 63;
    const int wv = tid >> 6;
    const int ml = lane & 15;
    const int q = lane >> 4;
    const int m0 = wv * 16;

    const floatx4 fzero = {0.f, 0.f, 0.f, 0.f};
    floatx4 acc[8];
#pragma unroll
    for (int i = 0; i < 8; ++i) acc[i] = fzero;

    for (int kc = 0; kc < 8; ++kc) {
        __syncthreads();
        {
            const int n = tid >> 1;
            const int half = tid & 1;
            const bf16x8* src = (const bf16x8*)(nW1t + n * 256 + kc * 32 + half * 16);
            bf16x8* dst = (bf16x8*)&sB[n * PB + half * 16];
            dst[0] = src[0];
            dst[1] = src[1];
        }
        __syncthreads();
        const bf16x8 a = *(const bf16x8*)&sA[(m0 + ml) * PN + kc * 32 + q * 8];
#pragma unroll
        for (int nt = 0; nt < 8; ++nt) {
            const bf16x8 b = *(const bf16x8*)&sB[(nt * 16 + ml) * PB + q * 8];
            acc[nt] = __builtin_amdgcn_mfma_f32_16x16x32_bf16(a, b, acc[nt], 0, 0, 0);
        }
    }

#pragma unroll
    for (int nt = 0; nt < 8; ++nt) {
        const float bias = biasF[256 + nt * 16 + ml];
#pragma unroll
        for (int r = 0; r < 4; ++r) {
            float v = acc[nt][r] + bias;
            sA[(m0 + q * 4 + r) * PN + nt * 16 + ml] = (bf16_t)fast_silu(v);
        }
    }
    __syncthreads();

    floatx4 acc2[8];
#pragma unroll
    for (int i = 0; i < 8; ++i) acc2[i] = fzero;

    for (int kc = 0; kc < 4; ++kc) {
        __syncthreads();
        {
            const int n = tid >> 1;
            const int half = tid & 1;
            const bf16x8* src = (const bf16x8*)(nW2t + n * 128 + kc * 32 + half * 16);
            bf16x8* dst = (bf16x8*)&sB[n * PB + half * 16];
            dst[0] = src[0];
            dst[1] = src[1];
        }
        __syncthreads();
        const bf16x8 a = *(const bf16x8*)&sA[(m0 + ml) * PN + kc * 32 + q * 8];
#pragma unroll
        for (int nt = 0; nt < 8; ++nt) {
            const bf16x8 b = *(const bf16x8*)&sB[(nt * 16 + ml) * PB + q * 8];
            acc2[nt] = __builtin_amdgcn_mfma_f32_16x16x32_bf16(a, b, acc2[nt], 0, 0, 0);
        }
    }

#pragma unroll
    for (int r = 0; r < 4; ++r) {
        const int n = n0 + m0 + q * 4 + r;
        if (n < NN) {
#pragma unroll
            for (int nt = 0; nt < 8; ++nt) {
                const int col = nt * 16 + ml;
                const size_t off = (size_t)n * DD + col;
                float v = acc2[nt][r] + biasF[384 + col];
                if (f32) {
                    float xv = ((const float*)x)[off];
                    ((float*)out)[off] = xv + v;
                } else {
                    float xv = (float)((const bf16_t*)x)[off];
                    ((bf16_t*)out)[off] = (bf16_t)(xv + v);
                }
            }
        }
    }
}

extern "C" void kernel_launch(void* const* d_in, const int* in_sizes, int n_in,
                              void* d_out, int out_size, void* d_ws, size_t ws_size,
                              hipStream_t stream)
{
    const void* x   = d_in[0];
    const void* ei  = d_in[1];
    const void* ea  = d_in[2];
    const void* eW1 = d_in[3];
    const void* eb1 = d_in[4];
    const void* eW2 = d_in[5];
    const void* eb2 = d_in[6];
    const void* nW1 = d_in[7];
    const void* nb1 = d_in[8];
    const void* nW2 = d_in[9];
    const void* nb2 = d_in[10];

    char* ws = (char*)d_ws;
    int*    flags  = (int*)ws;
    bf16_t* W1t    = (bf16_t*)(ws + W1T_OFF);
    bf16_t* W2t    = (bf16_t*)(ws + W2T_OFF);
    bf16_t* nW1t   = (bf16_t*)(ws + NW1T_OFF);
    bf16_t* nW2t   = (bf16_t*)(ws + NW2T_OFF);
    float*  biasF  = (float*)(ws + BIASF_OFF);
    bf16_t* xb     = (bf16_t*)(ws + XB_OFF);
    bf16_t* agg    = (bf16_t*)(ws + AGG_OFF);
    bf16_t* P      = (bf16_t*)(ws + P_OFF);
    bf16_t* Q      = (bf16_t*)(ws + Q_OFF);
    uint2*  epk    = (uint2*)(ws + EPK_OFF);
    int*    rstart = (int*)(ws + RSTART_OFF);
    int*    rcnt   = (int*)(ws + RCNT_OFF);
    int*    rofs   = (int*)(ws + ROFS_OFF);

    const int do_sort = (ws_size >= WS_V6) ? 1 : 0;

    if (do_sort)
        (void)hipMemsetAsync(rcnt, 0, (size_t)2 * NN * 4, stream);  // rcnt + rofs contiguous

    fused_prep_kernel<<<NB_K1, 256, 0, stream>>>(
        x, ei, eW1, eW2, nW1, nW2, eb1, eb2, nb1, nb2,
        W1t, W2t, nW1t, nW2t, biasF, xb, agg, rcnt, flags, do_sort);

    if (do_sort) {
        pq_kernel<<<(NN + 63) / 64 + 1, 256, 0, stream>>>(xb, W1t, P, Q, rcnt, rstart, 1);
        row_scatter_kernel<<<EE / 256, 256, 0, stream>>>(ei, rstart, rofs, epk, flags);
        edge_kernel_v6<<<NTILES, 256, 0, stream>>>(epk, ea, P, Q, W1t, W2t, biasF, agg, flags);
    } else if (ws_size >= WS_V3) {
        pq_kernel<<<(NN + 63) / 64, 256, 0, stream>>>(xb, W1t, P, Q, rcnt, rstart, 0);
        edge_kernel_v3<<<EE / 64, 256, 0, stream>>>(ei, ea, P, Q, W1t, W2t, biasF, agg, flags);
    } else {
        edge_kernel_v2<<<EE / 64, 256, 0, stream>>>(xb, ei, ea, W1t, W2t, biasF, agg, flags);
    }

    node_kernel_v3<<<(NN + 63) / 64, 256, 0, stream>>>(
        x, xb, agg, nW1t, nW2t, biasF, d_out, flags);
}